// Round 5
// baseline (378.760 us; speedup 1.0000x reference)
//
#include <hip/hip_runtime.h>
#include <math.h>
#include <float.h>

#define N_NODES 50000
#define N_EDGES 800000
#define TOT_E   850000          // N_EDGES + N_NODES self loops
#define IN_DIM  512
#define HID_DIM 64
#define OUT_DIM 40

// ---------------- Threefry-2x32, JAX-exact, key = (0, 42) ----------------
__device__ __forceinline__ unsigned rotl32(unsigned v, int n) {
  return (v << n) | (v >> (32 - n));
}

__device__ __forceinline__ void threefry2x32_0_42(unsigned x0, unsigned x1,
                                                  unsigned &o0, unsigned &o1) {
  const unsigned ks0 = 0u;
  const unsigned ks1 = 42u;
  const unsigned ks2 = 0u ^ 42u ^ 0x1BD11BDAu;
  x0 += ks0; x1 += ks1;
  x0 += x1; x1 = rotl32(x1, 13); x1 ^= x0;
  x0 += x1; x1 = rotl32(x1, 15); x1 ^= x0;
  x0 += x1; x1 = rotl32(x1, 26); x1 ^= x0;
  x0 += x1; x1 = rotl32(x1,  6); x1 ^= x0;
  x0 += ks1; x1 += ks2 + 1u;
  x0 += x1; x1 = rotl32(x1, 17); x1 ^= x0;
  x0 += x1; x1 = rotl32(x1, 29); x1 ^= x0;
  x0 += x1; x1 = rotl32(x1, 16); x1 ^= x0;
  x0 += x1; x1 = rotl32(x1, 24); x1 ^= x0;
  x0 += ks2; x1 += ks0 + 2u;
  x0 += x1; x1 = rotl32(x1, 13); x1 ^= x0;
  x0 += x1; x1 = rotl32(x1, 15); x1 ^= x0;
  x0 += x1; x1 = rotl32(x1, 26); x1 ^= x0;
  x0 += x1; x1 = rotl32(x1,  6); x1 ^= x0;
  x0 += ks0; x1 += ks1 + 3u;
  x0 += x1; x1 = rotl32(x1, 17); x1 ^= x0;
  x0 += x1; x1 = rotl32(x1, 29); x1 ^= x0;
  x0 += x1; x1 = rotl32(x1, 16); x1 ^= x0;
  x0 += x1; x1 = rotl32(x1, 24); x1 ^= x0;
  x0 += ks1; x1 += ks2 + 4u;
  x0 += x1; x1 = rotl32(x1, 13); x1 ^= x0;
  x0 += x1; x1 = rotl32(x1, 15); x1 ^= x0;
  x0 += x1; x1 = rotl32(x1, 26); x1 ^= x0;
  x0 += x1; x1 = rotl32(x1,  6); x1 ^= x0;
  x0 += ks2; x1 += ks0 + 5u;
  o0 = x0; o1 = x1;
}

// ---------------- CSR build ----------------
__global__ void k_count(const int* __restrict__ dst, int* __restrict__ counts) {
  int e = blockIdx.x * 256 + threadIdx.x;
  if (e < N_EDGES) atomicAdd(&counts[dst[e]], 1);
}

__global__ __launch_bounds__(1024) void k_scan1(const int* __restrict__ counts,
                                                int* __restrict__ offsets,
                                                int* __restrict__ bsums) {
  __shared__ int sm[1024];
  int tid = threadIdx.x;
  int idx = blockIdx.x * 1024 + tid;
  int val = (idx < N_NODES) ? counts[idx] + 1 : 0;
  sm[tid] = val;
  __syncthreads();
  for (int off = 1; off < 1024; off <<= 1) {
    int t = (tid >= off) ? sm[tid - off] : 0;
    __syncthreads();
    sm[tid] += t;
    __syncthreads();
  }
  if (idx < N_NODES) offsets[idx] = sm[tid];
  if (tid == 1023) bsums[blockIdx.x] = sm[1023];
}

__global__ void k_scan2(const int* __restrict__ bsums, int* __restrict__ bexcl) {
  int lane = threadIdx.x;
  int orig = (lane < 49) ? bsums[lane] : 0;
  int v = orig;
  for (int off = 1; off < 64; off <<= 1) {
    int u = __shfl_up(v, off, 64);
    if (lane >= off) v += u;
  }
  if (lane < 64) bexcl[lane] = v - orig;
}

__global__ __launch_bounds__(1024) void k_scan3(const int* __restrict__ counts,
                                                int* __restrict__ offsets,
                                                int* __restrict__ cursor,
                                                float* __restrict__ dis,
                                                int* __restrict__ elist,
                                                const int* __restrict__ bexcl) {
  int idx = blockIdx.x * 1024 + threadIdx.x;
  if (idx >= N_NODES) return;
  int val = counts[idx] + 1;
  int incl = offsets[idx] + bexcl[blockIdx.x];
  int excl = incl - val;
  offsets[idx] = excl;
  cursor[idx] = excl;
  dis[idx] = rsqrtf((float)val);
  elist[incl - 1] = idx;                    // self-loop in last slot
  if (idx == N_NODES - 1) offsets[N_NODES] = incl;  // == TOT_E
}

__global__ void k_fill(const int* __restrict__ ei, int* __restrict__ cursor,
                       int* __restrict__ elist) {
  int e = blockIdx.x * 256 + threadIdx.x;
  if (e >= N_EDGES) return;
  int s = ei[e], d = ei[N_EDGES + e];
  int pos = atomicAdd(&cursor[d], 1);
  elist[pos] = s;
}

// ---------------- weight repack ----------------
__global__ void k_wprep(const float* __restrict__ W1, const float* __restrict__ W2,
                        float* __restrict__ Wp1, float* __restrict__ Wp2) {
  int i = blockIdx.x * 256 + threadIdx.x;
  if (i < IN_DIM * HID_DIM) {
    int k = i >> 6, c = i & 63;
    Wp1[((k >> 2) << 8) + (c << 2) + (k & 3)] = W1[i];
  }
  if (i < HID_DIM * OUT_DIM) {
    int k = i / OUT_DIM, c = i - k * OUT_DIM;
    Wp2[(k >> 2) * (OUT_DIM * 4) + (c << 2) + (k & 3)] = W2[i];
  }
}

// ---------------- GEMM1: ht1s = dis[row] * (x @ W1) ----------------
// 8 waves/block share 64 rows (L1 reuse); wave w owns cols 8w..8w+7 (W scalar)
__global__ __launch_bounds__(512) void k_gemm1(const float* __restrict__ x,
                                               const float* __restrict__ Wp1,
                                               const float* __restrict__ dis,
                                               float* __restrict__ ht1s) {
  const int lane = threadIdx.x & 63;
  const int wave = threadIdx.x >> 6;                    // 0..7
  const int cg = __builtin_amdgcn_readfirstlane(wave);  // col group (8 cols)
  const int row = blockIdx.x * 64 + lane;
  const bool valid = row < N_NODES;
  const float4* __restrict__ xrow =
      (const float4*)(x + (size_t)(valid ? row : 0) * IN_DIM);

  float acc[8];
#pragma unroll
  for (int i = 0; i < 8; ++i) acc[i] = 0.0f;

#pragma unroll 2
  for (int k0 = 0; k0 < IN_DIM; k0 += 4) {
    float4 x4 = xrow[k0 >> 2];
    const float4* __restrict__ wv = (const float4*)(Wp1 + (k0 >> 2) * 256 + cg * 32);
#pragma unroll
    for (int c = 0; c < 8; ++c) {
      float4 w = wv[c];
      acc[c] += x4.x * w.x;
      acc[c] += x4.y * w.y;
      acc[c] += x4.z * w.z;
      acc[c] += x4.w * w.w;
    }
  }
  if (valid) {
    float dr = dis[row];
    float* __restrict__ o = ht1s + (size_t)row * HID_DIM + cg * 8;
#pragma unroll
    for (int c = 0; c < 8; ++c) o[c] = acc[c] * dr;
  }
}

// ---------------- agg1: h[d] = dropout(relu(dis[d]*sum ht1s[src] + b1)) -----
__global__ __launch_bounds__(256) void k_agg1(const int* __restrict__ offsets,
                                              const int* __restrict__ elist,
                                              const float* __restrict__ dis,
                                              const float* __restrict__ ht1s,
                                              const float* __restrict__ b1,
                                              float* __restrict__ h) {
  const int wave = threadIdx.x >> 6;
  const int lane = threadIdx.x & 63;
  const int d = blockIdx.x * 4 + wave;
  const int g = lane >> 4;        // edge group 0..3
  const int fl = lane & 15;       // feature quad 0..15

  const int begin = offsets[d], end = offsets[d + 1];
  float4 acc = {0.f, 0.f, 0.f, 0.f};
  for (int j = begin + g; j < end; j += 4) {
    int s = elist[j];
    const float4 v = *(const float4*)(ht1s + (size_t)s * HID_DIM + fl * 4);
    acc.x += v.x; acc.y += v.y; acc.z += v.z; acc.w += v.w;
  }
  acc.x += __shfl_xor(acc.x, 32); acc.y += __shfl_xor(acc.y, 32);
  acc.z += __shfl_xor(acc.z, 32); acc.w += __shfl_xor(acc.w, 32);
  acc.x += __shfl_xor(acc.x, 16); acc.y += __shfl_xor(acc.y, 16);
  acc.z += __shfl_xor(acc.z, 16); acc.w += __shfl_xor(acc.w, 16);

  if (lane < 16) {
    float dd = dis[d];
    float4 bb = *(const float4*)(b1 + lane * 4);
    float4 v;
    v.x = fmaxf(acc.x * dd + bb.x, 0.f);
    v.y = fmaxf(acc.y * dd + bb.y, 0.f);
    v.z = fmaxf(acc.z * dd + bb.z, 0.f);
    v.w = fmaxf(acc.w * dd + bb.w, 0.f);
    unsigned base = (unsigned)d * 64u + (unsigned)lane * 4u;
    unsigned o0, o1;
    threefry2x32_0_42(0u, base + 0u, o0, o1);
    v.x = ((o0 ^ o1) & 0x80000000u) ? 0.f : v.x * 2.f;
    threefry2x32_0_42(0u, base + 1u, o0, o1);
    v.y = ((o0 ^ o1) & 0x80000000u) ? 0.f : v.y * 2.f;
    threefry2x32_0_42(0u, base + 2u, o0, o1);
    v.z = ((o0 ^ o1) & 0x80000000u) ? 0.f : v.z * 2.f;
    threefry2x32_0_42(0u, base + 3u, o0, o1);
    v.w = ((o0 ^ o1) & 0x80000000u) ? 0.f : v.w * 2.f;
    *(float4*)(h + (size_t)d * HID_DIM + lane * 4) = v;
  }
}

// ---------------- GEMM2: ht2s = dis[row] * (h @ W2) ----------------
// 8 waves/block share 64 rows; wave w owns cols 5w..5w+4
__global__ __launch_bounds__(512) void k_gemm2(const float* __restrict__ h,
                                               const float* __restrict__ Wp2,
                                               const float* __restrict__ dis,
                                               float* __restrict__ ht2s) {
  const int lane = threadIdx.x & 63;
  const int wave = threadIdx.x >> 6;                    // 0..7
  const int cg = __builtin_amdgcn_readfirstlane(wave);  // col group (5 cols)
  const int row = blockIdx.x * 64 + lane;
  const bool valid = row < N_NODES;
  const float4* __restrict__ hrow =
      (const float4*)(h + (size_t)(valid ? row : 0) * HID_DIM);

  float acc[5];
#pragma unroll
  for (int i = 0; i < 5; ++i) acc[i] = 0.0f;

#pragma unroll 2
  for (int k0 = 0; k0 < HID_DIM; k0 += 4) {
    float4 x4 = hrow[k0 >> 2];
    const float4* __restrict__ wv = (const float4*)(Wp2 + (k0 >> 2) * 160 + cg * 20);
#pragma unroll
    for (int c = 0; c < 5; ++c) {
      float4 w = wv[c];
      acc[c] += x4.x * w.x;
      acc[c] += x4.y * w.y;
      acc[c] += x4.z * w.z;
      acc[c] += x4.w * w.w;
    }
  }
  if (valid) {
    float dr = dis[row];
    float* __restrict__ o = ht2s + (size_t)row * OUT_DIM + cg * 5;
#pragma unroll
    for (int c = 0; c < 5; ++c) o[c] = acc[c] * dr;
  }
}

// ---------------- agg2 + bias2 + log-softmax, fused ----------------
__global__ __launch_bounds__(256) void k_agg2(const int* __restrict__ offsets,
                                              const int* __restrict__ elist,
                                              const float* __restrict__ dis,
                                              const float* __restrict__ ht2s,
                                              const float* __restrict__ b2,
                                              float* __restrict__ out) {
  const int wave = threadIdx.x >> 6;
  const int lane = threadIdx.x & 63;
  const int d = blockIdx.x * 4 + wave;

  const int begin = offsets[d], end = offsets[d + 1];
  float acc = 0.f;
  if (lane < OUT_DIM) {
    for (int j = begin; j < end; ++j) {
      int s = elist[j];
      acc += ht2s[(size_t)s * OUT_DIM + lane];
    }
  }
  float v = (lane < OUT_DIM) ? acc * dis[d] + b2[lane] : -FLT_MAX;
  float m = v;
  m = fmaxf(m, __shfl_xor(m, 1));
  m = fmaxf(m, __shfl_xor(m, 2));
  m = fmaxf(m, __shfl_xor(m, 4));
  m = fmaxf(m, __shfl_xor(m, 8));
  m = fmaxf(m, __shfl_xor(m, 16));
  m = fmaxf(m, __shfl_xor(m, 32));
  float e = (lane < OUT_DIM) ? expf(v - m) : 0.f;
  e += __shfl_xor(e, 1);
  e += __shfl_xor(e, 2);
  e += __shfl_xor(e, 4);
  e += __shfl_xor(e, 8);
  e += __shfl_xor(e, 16);
  e += __shfl_xor(e, 32);
  float ls = logf(e) + m;
  if (lane < OUT_DIM) out[(size_t)d * OUT_DIM + lane] = v - ls;
}

// ---------------- launch ----------------
extern "C" void kernel_launch(void* const* d_in, const int* in_sizes, int n_in,
                              void* d_out, int out_size, void* d_ws, size_t ws_size,
                              hipStream_t stream) {
  const float* x  = (const float*)d_in[0];
  const int*   ei = (const int*)  d_in[1];
  const float* W1 = (const float*)d_in[2];
  const float* b1 = (const float*)d_in[3];
  const float* W2 = (const float*)d_in[4];
  const float* b2 = (const float*)d_in[5];
  float* out = (float*)d_out;
  float* ws  = (float*)d_ws;

  // ws layout
  float* ht   = ws;                         // 3,200,000  (ht1s, later ht2s)
  float* h    = ws + 3200000;               // 3,200,000
  float* dis  = ws + 6400000;               // 51,200
  float* Wp1  = ws + 6451200;               // 32,768
  float* Wp2  = ws + 6483968;               // 2,560
  int* ibase  = (int*)(ws + 6486528);
  int* counts  = ibase;                     // 51,200
  int* offsets = ibase + 51200;             // 51,264 (needs 50001)
  int* cursor  = ibase + 102464;            // 51,200
  int* elist   = ibase + 153664;            // 850,000
  int* bsums   = ibase + 1003664;           // 64
  int* bexcl   = ibase + 1003728;           // 64

  hipMemsetAsync(counts, 0, (size_t)N_NODES * sizeof(int), stream);

  k_count<<<3125, 256, 0, stream>>>(ei + N_EDGES, counts);
  k_scan1<<<49, 1024, 0, stream>>>(counts, offsets, bsums);
  k_scan2<<<1, 64, 0, stream>>>(bsums, bexcl);
  k_scan3<<<49, 1024, 0, stream>>>(counts, offsets, cursor, dis, elist, bexcl);
  k_fill<<<3125, 256, 0, stream>>>(ei, cursor, elist);

  k_wprep<<<128, 256, 0, stream>>>(W1, W2, Wp1, Wp2);
  k_gemm1<<<782, 512, 0, stream>>>(x, Wp1, dis, ht);
  k_agg1<<<12500, 256, 0, stream>>>(offsets, elist, dis, ht, b1, h);
  k_gemm2<<<782, 512, 0, stream>>>(h, Wp2, dis, ht);
  k_agg2<<<12500, 256, 0, stream>>>(offsets, elist, dis, ht, b2, out);
}

// Round 6
// 327.764 us; speedup vs baseline: 1.1556x; 1.1556x over previous
//
#include <hip/hip_runtime.h>
#include <math.h>
#include <float.h>

#define N_NODES 50000
#define N_EDGES 800000
#define TOT_E   850000          // N_EDGES + N_NODES self loops
#define IN_DIM  512
#define HID_DIM 64
#define OUT_DIM 40

// ---------------- Threefry-2x32, JAX-exact, key = (0, 42) ----------------
__device__ __forceinline__ unsigned rotl32(unsigned v, int n) {
  return (v << n) | (v >> (32 - n));
}

__device__ __forceinline__ void threefry2x32_0_42(unsigned x0, unsigned x1,
                                                  unsigned &o0, unsigned &o1) {
  const unsigned ks0 = 0u;
  const unsigned ks1 = 42u;
  const unsigned ks2 = 0u ^ 42u ^ 0x1BD11BDAu;
  x0 += ks0; x1 += ks1;
  x0 += x1; x1 = rotl32(x1, 13); x1 ^= x0;
  x0 += x1; x1 = rotl32(x1, 15); x1 ^= x0;
  x0 += x1; x1 = rotl32(x1, 26); x1 ^= x0;
  x0 += x1; x1 = rotl32(x1,  6); x1 ^= x0;
  x0 += ks1; x1 += ks2 + 1u;
  x0 += x1; x1 = rotl32(x1, 17); x1 ^= x0;
  x0 += x1; x1 = rotl32(x1, 29); x1 ^= x0;
  x0 += x1; x1 = rotl32(x1, 16); x1 ^= x0;
  x0 += x1; x1 = rotl32(x1, 24); x1 ^= x0;
  x0 += ks2; x1 += ks0 + 2u;
  x0 += x1; x1 = rotl32(x1, 13); x1 ^= x0;
  x0 += x1; x1 = rotl32(x1, 15); x1 ^= x0;
  x0 += x1; x1 = rotl32(x1, 26); x1 ^= x0;
  x0 += x1; x1 = rotl32(x1,  6); x1 ^= x0;
  x0 += ks0; x1 += ks1 + 3u;
  x0 += x1; x1 = rotl32(x1, 17); x1 ^= x0;
  x0 += x1; x1 = rotl32(x1, 29); x1 ^= x0;
  x0 += x1; x1 = rotl32(x1, 16); x1 ^= x0;
  x0 += x1; x1 = rotl32(x1, 24); x1 ^= x0;
  x0 += ks1; x1 += ks2 + 4u;
  x0 += x1; x1 = rotl32(x1, 13); x1 ^= x0;
  x0 += x1; x1 = rotl32(x1, 15); x1 ^= x0;
  x0 += x1; x1 = rotl32(x1, 26); x1 ^= x0;
  x0 += x1; x1 = rotl32(x1,  6); x1 ^= x0;
  x0 += ks2; x1 += ks0 + 5u;
  o0 = x0; o1 = x1;
}

// ---------------- CSR build ----------------
__global__ void k_count(const int* __restrict__ dst, int* __restrict__ counts) {
  int e = blockIdx.x * 256 + threadIdx.x;
  if (e < N_EDGES) atomicAdd(&counts[dst[e]], 1);
}

__global__ __launch_bounds__(1024) void k_scan1(const int* __restrict__ counts,
                                                int* __restrict__ offsets,
                                                int* __restrict__ bsums) {
  __shared__ int sm[1024];
  int tid = threadIdx.x;
  int idx = blockIdx.x * 1024 + tid;
  int val = (idx < N_NODES) ? counts[idx] + 1 : 0;
  sm[tid] = val;
  __syncthreads();
  for (int off = 1; off < 1024; off <<= 1) {
    int t = (tid >= off) ? sm[tid - off] : 0;
    __syncthreads();
    sm[tid] += t;
    __syncthreads();
  }
  if (idx < N_NODES) offsets[idx] = sm[tid];
  if (tid == 1023) bsums[blockIdx.x] = sm[1023];
}

__global__ void k_scan2(const int* __restrict__ bsums, int* __restrict__ bexcl) {
  int lane = threadIdx.x;
  int orig = (lane < 49) ? bsums[lane] : 0;
  int v = orig;
  for (int off = 1; off < 64; off <<= 1) {
    int u = __shfl_up(v, off, 64);
    if (lane >= off) v += u;
  }
  if (lane < 64) bexcl[lane] = v - orig;
}

__global__ __launch_bounds__(1024) void k_scan3(const int* __restrict__ counts,
                                                int* __restrict__ offsets,
                                                int* __restrict__ cursor,
                                                float* __restrict__ dis,
                                                int* __restrict__ elist,
                                                const int* __restrict__ bexcl) {
  int idx = blockIdx.x * 1024 + threadIdx.x;
  if (idx >= N_NODES) return;
  int val = counts[idx] + 1;
  int incl = offsets[idx] + bexcl[blockIdx.x];
  int excl = incl - val;
  offsets[idx] = excl;
  cursor[idx] = excl;
  dis[idx] = rsqrtf((float)val);
  elist[incl - 1] = idx;                    // self-loop in last slot
  if (idx == N_NODES - 1) offsets[N_NODES] = incl;  // == TOT_E
}

__global__ void k_fill(const int* __restrict__ ei, int* __restrict__ cursor,
                       int* __restrict__ elist) {
  int e = blockIdx.x * 256 + threadIdx.x;
  if (e >= N_EDGES) return;
  int s = ei[e], d = ei[N_EDGES + e];
  int pos = atomicAdd(&cursor[d], 1);
  elist[pos] = s;
}

// ---------------- weight repack ----------------
__global__ void k_wprep(const float* __restrict__ W1, const float* __restrict__ W2,
                        float* __restrict__ Wp1, float* __restrict__ Wp2) {
  int i = blockIdx.x * 256 + threadIdx.x;
  if (i < IN_DIM * HID_DIM) {
    int k = i >> 6, c = i & 63;
    Wp1[((k >> 2) << 8) + (c << 2) + (k & 3)] = W1[i];
  }
  if (i < HID_DIM * OUT_DIM) {
    int k = i / OUT_DIM, c = i - k * OUT_DIM;
    Wp2[(k >> 2) * (OUT_DIM * 4) + (c << 2) + (k & 3)] = W2[i];
  }
}

// ---------------- GEMM1: ht1s = dis[row] * (x @ W1) ----------------
// LDS-staged x tile (coalesced global loads, stride-65 pad => 2-way banks),
// double-buffered; 4 waves x 16 cols, W via wave-uniform scalar loads.
#define LDS_STRIDE 65
__global__ __launch_bounds__(256) void k_gemm1(const float* __restrict__ x,
                                               const float* __restrict__ Wp1,
                                               const float* __restrict__ dis,
                                               float* __restrict__ ht1s) {
  __shared__ float sx[2][64 * LDS_STRIDE];
  const int tid = threadIdx.x;
  const int lane = tid & 63;
  const int wave = tid >> 6;
  const int cg = __builtin_amdgcn_readfirstlane(wave);  // 16-col group
  const int brow = blockIdx.x * 64;
  const int row = brow + lane;
  const bool valid = row < N_NODES;

  // staging mapping: thread -> (srow in 0..15, fq in 0..15), rows += 16 per j
  const int fq = tid & 15;
  const int sr = tid >> 4;

  float acc[16];
#pragma unroll
  for (int i = 0; i < 16; ++i) acc[i] = 0.0f;

  // ---- stage chunk 0 ----
#pragma unroll
  for (int j = 0; j < 4; ++j) {
    int r = sr + j * 16;
    int gr = brow + r;
    gr = gr < N_NODES ? gr : N_NODES - 1;
    float4 v = *(const float4*)(x + (size_t)gr * IN_DIM + fq * 4);
    int base = r * LDS_STRIDE + fq * 4;
    sx[0][base + 0] = v.x; sx[0][base + 1] = v.y;
    sx[0][base + 2] = v.z; sx[0][base + 3] = v.w;
  }
  __syncthreads();

  int buf = 0;
  for (int kc = 0; kc < IN_DIM / 64; ++kc) {
    const int k0 = kc * 64;
    // ---- stage next chunk into other buffer (overlaps compute) ----
    if (kc < IN_DIM / 64 - 1) {
#pragma unroll
      for (int j = 0; j < 4; ++j) {
        int r = sr + j * 16;
        int gr = brow + r;
        gr = gr < N_NODES ? gr : N_NODES - 1;
        float4 v = *(const float4*)(x + (size_t)gr * IN_DIM + k0 + 64 + fq * 4);
        int base = r * LDS_STRIDE + fq * 4;
        sx[buf ^ 1][base + 0] = v.x; sx[buf ^ 1][base + 1] = v.y;
        sx[buf ^ 1][base + 2] = v.z; sx[buf ^ 1][base + 3] = v.w;
      }
    }
    // ---- compute on current buffer ----
    const float* __restrict__ xs = &sx[buf][lane * LDS_STRIDE];
#pragma unroll 2
    for (int q = 0; q < 16; ++q) {
      float x0 = xs[q * 4 + 0];
      float x1 = xs[q * 4 + 1];
      float x2 = xs[q * 4 + 2];
      float x3 = xs[q * 4 + 3];
      const float4* __restrict__ wv =
          (const float4*)(Wp1 + ((k0 >> 2) + q) * 256 + cg * 64);
#pragma unroll
      for (int c = 0; c < 16; ++c) {
        float4 w = wv[c];
        acc[c] += x0 * w.x;
        acc[c] += x1 * w.y;
        acc[c] += x2 * w.z;
        acc[c] += x3 * w.w;
      }
    }
    __syncthreads();
    buf ^= 1;
  }

  if (valid) {
    float dr = dis[row];
    float* __restrict__ o = ht1s + (size_t)row * HID_DIM + cg * 16;
#pragma unroll
    for (int c = 0; c < 16; ++c) o[c] = acc[c] * dr;
  }
}

// ---------------- agg1: h[d] = dropout(relu(dis[d]*sum ht1s[src] + b1)) -----
__global__ __launch_bounds__(256) void k_agg1(const int* __restrict__ offsets,
                                              const int* __restrict__ elist,
                                              const float* __restrict__ dis,
                                              const float* __restrict__ ht1s,
                                              const float* __restrict__ b1,
                                              float* __restrict__ h) {
  const int wave = threadIdx.x >> 6;
  const int lane = threadIdx.x & 63;
  const int d = blockIdx.x * 4 + wave;
  const int g = lane >> 4;        // edge group 0..3
  const int fl = lane & 15;       // feature quad 0..15

  const int begin = offsets[d], end = offsets[d + 1];
  float4 acc = {0.f, 0.f, 0.f, 0.f};
  for (int j = begin + g; j < end; j += 4) {
    int s = elist[j];
    const float4 v = *(const float4*)(ht1s + (size_t)s * HID_DIM + fl * 4);
    acc.x += v.x; acc.y += v.y; acc.z += v.z; acc.w += v.w;
  }
  acc.x += __shfl_xor(acc.x, 32); acc.y += __shfl_xor(acc.y, 32);
  acc.z += __shfl_xor(acc.z, 32); acc.w += __shfl_xor(acc.w, 32);
  acc.x += __shfl_xor(acc.x, 16); acc.y += __shfl_xor(acc.y, 16);
  acc.z += __shfl_xor(acc.z, 16); acc.w += __shfl_xor(acc.w, 16);

  if (lane < 16) {
    float dd = dis[d];
    float4 bb = *(const float4*)(b1 + lane * 4);
    float4 v;
    v.x = fmaxf(acc.x * dd + bb.x, 0.f);
    v.y = fmaxf(acc.y * dd + bb.y, 0.f);
    v.z = fmaxf(acc.z * dd + bb.z, 0.f);
    v.w = fmaxf(acc.w * dd + bb.w, 0.f);
    unsigned base = (unsigned)d * 64u + (unsigned)lane * 4u;
    unsigned o0, o1;
    threefry2x32_0_42(0u, base + 0u, o0, o1);
    v.x = ((o0 ^ o1) & 0x80000000u) ? 0.f : v.x * 2.f;
    threefry2x32_0_42(0u, base + 1u, o0, o1);
    v.y = ((o0 ^ o1) & 0x80000000u) ? 0.f : v.y * 2.f;
    threefry2x32_0_42(0u, base + 2u, o0, o1);
    v.z = ((o0 ^ o1) & 0x80000000u) ? 0.f : v.z * 2.f;
    threefry2x32_0_42(0u, base + 3u, o0, o1);
    v.w = ((o0 ^ o1) & 0x80000000u) ? 0.f : v.w * 2.f;
    *(float4*)(h + (size_t)d * HID_DIM + lane * 4) = v;
  }
}

// ---------------- GEMM2: ht2s = dis[row] * (h @ W2)  (round-3 shape) --------
__global__ __launch_bounds__(256) void k_gemm2(const float* __restrict__ h,
                                               const float* __restrict__ Wp2,
                                               const float* __restrict__ dis,
                                               float* __restrict__ ht2s) {
  const int lane = threadIdx.x & 63;
  const int wave = threadIdx.x >> 6;                       // 0..3
  const int cg = __builtin_amdgcn_readfirstlane(wave & 1); // 0/1
  const int rb = wave >> 1;                                // 0/1
  const int row = blockIdx.x * 128 + rb * 64 + lane;
  const bool valid = row < N_NODES;
  const float4* __restrict__ hrow =
      (const float4*)(h + (size_t)(valid ? row : 0) * HID_DIM);

  float acc[20];
#pragma unroll
  for (int i = 0; i < 20; ++i) acc[i] = 0.0f;

#pragma unroll 2
  for (int k0 = 0; k0 < HID_DIM; k0 += 4) {
    float4 x4 = hrow[k0 >> 2];
    const float4* __restrict__ wv = (const float4*)(Wp2 + (k0 >> 2) * 160 + cg * 80);
#pragma unroll
    for (int c = 0; c < 20; ++c) {
      float4 w = wv[c];
      acc[c] += x4.x * w.x;
      acc[c] += x4.y * w.y;
      acc[c] += x4.z * w.z;
      acc[c] += x4.w * w.w;
    }
  }
  if (valid) {
    float dr = dis[row];
    float* __restrict__ o = ht2s + (size_t)row * OUT_DIM + cg * 20;
#pragma unroll
    for (int c = 0; c < 20; ++c) o[c] = acc[c] * dr;
  }
}

// ---------------- agg2 + bias2 + log-softmax, fused ----------------
__global__ __launch_bounds__(256) void k_agg2(const int* __restrict__ offsets,
                                              const int* __restrict__ elist,
                                              const float* __restrict__ dis,
                                              const float* __restrict__ ht2s,
                                              const float* __restrict__ b2,
                                              float* __restrict__ out) {
  const int wave = threadIdx.x >> 6;
  const int lane = threadIdx.x & 63;
  const int d = blockIdx.x * 4 + wave;

  const int begin = offsets[d], end = offsets[d + 1];
  float acc = 0.f;
  if (lane < OUT_DIM) {
    for (int j = begin; j < end; ++j) {
      int s = elist[j];
      acc += ht2s[(size_t)s * OUT_DIM + lane];
    }
  }
  float v = (lane < OUT_DIM) ? acc * dis[d] + b2[lane] : -FLT_MAX;
  float m = v;
  m = fmaxf(m, __shfl_xor(m, 1));
  m = fmaxf(m, __shfl_xor(m, 2));
  m = fmaxf(m, __shfl_xor(m, 4));
  m = fmaxf(m, __shfl_xor(m, 8));
  m = fmaxf(m, __shfl_xor(m, 16));
  m = fmaxf(m, __shfl_xor(m, 32));
  float e = (lane < OUT_DIM) ? expf(v - m) : 0.f;
  e += __shfl_xor(e, 1);
  e += __shfl_xor(e, 2);
  e += __shfl_xor(e, 4);
  e += __shfl_xor(e, 8);
  e += __shfl_xor(e, 16);
  e += __shfl_xor(e, 32);
  float ls = logf(e) + m;
  if (lane < OUT_DIM) out[(size_t)d * OUT_DIM + lane] = v - ls;
}

// ---------------- launch ----------------
extern "C" void kernel_launch(void* const* d_in, const int* in_sizes, int n_in,
                              void* d_out, int out_size, void* d_ws, size_t ws_size,
                              hipStream_t stream) {
  const float* x  = (const float*)d_in[0];
  const int*   ei = (const int*)  d_in[1];
  const float* W1 = (const float*)d_in[2];
  const float* b1 = (const float*)d_in[3];
  const float* W2 = (const float*)d_in[4];
  const float* b2 = (const float*)d_in[5];
  float* out = (float*)d_out;
  float* ws  = (float*)d_ws;

  // ws layout
  float* ht   = ws;                         // 3,200,000  (ht1s, later ht2s)
  float* h    = ws + 3200000;               // 3,200,000
  float* dis  = ws + 6400000;               // 51,200
  float* Wp1  = ws + 6451200;               // 32,768
  float* Wp2  = ws + 6483968;               // 2,560
  int* ibase  = (int*)(ws + 6486528);
  int* counts  = ibase;                     // 51,200
  int* offsets = ibase + 51200;             // 51,264 (needs 50001)
  int* cursor  = ibase + 102464;            // 51,200
  int* elist   = ibase + 153664;            // 850,000
  int* bsums   = ibase + 1003664;           // 64
  int* bexcl   = ibase + 1003728;           // 64

  hipMemsetAsync(counts, 0, (size_t)N_NODES * sizeof(int), stream);

  k_count<<<3125, 256, 0, stream>>>(ei + N_EDGES, counts);
  k_scan1<<<49, 1024, 0, stream>>>(counts, offsets, bsums);
  k_scan2<<<1, 64, 0, stream>>>(bsums, bexcl);
  k_scan3<<<49, 1024, 0, stream>>>(counts, offsets, cursor, dis, elist, bexcl);
  k_fill<<<3125, 256, 0, stream>>>(ei, cursor, elist);

  k_wprep<<<128, 256, 0, stream>>>(W1, W2, Wp1, Wp2);
  k_gemm1<<<782, 256, 0, stream>>>(x, Wp1, dis, ht);
  k_agg1<<<12500, 256, 0, stream>>>(offsets, elist, dis, ht, b1, h);
  k_gemm2<<<391, 256, 0, stream>>>(h, Wp2, dis, ht);
  k_agg2<<<12500, 256, 0, stream>>>(offsets, elist, dis, ht, b2, out);
}

// Round 7
// 269.171 us; speedup vs baseline: 1.4071x; 1.2177x over previous
//
#include <hip/hip_runtime.h>
#include <math.h>
#include <float.h>

#define N_NODES 50000
#define N_EDGES 800000
#define TOT_E   850000          // N_EDGES + N_NODES self loops
#define IN_DIM  512
#define HID_DIM 64
#define OUT_DIM 40

typedef __attribute__((ext_vector_type(8))) short bf16x8;
typedef __attribute__((ext_vector_type(4))) float f32x4;

// ---------------- Threefry-2x32, JAX-exact, key = (0, 42) ----------------
__device__ __forceinline__ unsigned rotl32(unsigned v, int n) {
  return (v << n) | (v >> (32 - n));
}

__device__ __forceinline__ void threefry2x32_0_42(unsigned x0, unsigned x1,
                                                  unsigned &o0, unsigned &o1) {
  const unsigned ks0 = 0u;
  const unsigned ks1 = 42u;
  const unsigned ks2 = 0u ^ 42u ^ 0x1BD11BDAu;
  x0 += ks0; x1 += ks1;
  x0 += x1; x1 = rotl32(x1, 13); x1 ^= x0;
  x0 += x1; x1 = rotl32(x1, 15); x1 ^= x0;
  x0 += x1; x1 = rotl32(x1, 26); x1 ^= x0;
  x0 += x1; x1 = rotl32(x1,  6); x1 ^= x0;
  x0 += ks1; x1 += ks2 + 1u;
  x0 += x1; x1 = rotl32(x1, 17); x1 ^= x0;
  x0 += x1; x1 = rotl32(x1, 29); x1 ^= x0;
  x0 += x1; x1 = rotl32(x1, 16); x1 ^= x0;
  x0 += x1; x1 = rotl32(x1, 24); x1 ^= x0;
  x0 += ks2; x1 += ks0 + 2u;
  x0 += x1; x1 = rotl32(x1, 13); x1 ^= x0;
  x0 += x1; x1 = rotl32(x1, 15); x1 ^= x0;
  x0 += x1; x1 = rotl32(x1, 26); x1 ^= x0;
  x0 += x1; x1 = rotl32(x1,  6); x1 ^= x0;
  x0 += ks0; x1 += ks1 + 3u;
  x0 += x1; x1 = rotl32(x1, 17); x1 ^= x0;
  x0 += x1; x1 = rotl32(x1, 29); x1 ^= x0;
  x0 += x1; x1 = rotl32(x1, 16); x1 ^= x0;
  x0 += x1; x1 = rotl32(x1, 24); x1 ^= x0;
  x0 += ks1; x1 += ks2 + 4u;
  x0 += x1; x1 = rotl32(x1, 13); x1 ^= x0;
  x0 += x1; x1 = rotl32(x1, 15); x1 ^= x0;
  x0 += x1; x1 = rotl32(x1, 26); x1 ^= x0;
  x0 += x1; x1 = rotl32(x1,  6); x1 ^= x0;
  x0 += ks2; x1 += ks0 + 5u;
  o0 = x0; o1 = x1;
}

__device__ __forceinline__ unsigned short f2bf(float f) {
  unsigned u = __float_as_uint(f);
  unsigned r = u + 0x7FFFu + ((u >> 16) & 1u);   // RNE
  return (unsigned short)(r >> 16);
}

// ---------------- CSR build ----------------
__global__ void k_count(const int* __restrict__ dst, int* __restrict__ counts) {
  int e = blockIdx.x * 256 + threadIdx.x;
  if (e < N_EDGES) atomicAdd(&counts[dst[e]], 1);
}

__global__ __launch_bounds__(1024) void k_scan1(const int* __restrict__ counts,
                                                int* __restrict__ offsets,
                                                int* __restrict__ bsums) {
  __shared__ int sm[1024];
  int tid = threadIdx.x;
  int idx = blockIdx.x * 1024 + tid;
  int val = (idx < N_NODES) ? counts[idx] + 1 : 0;
  sm[tid] = val;
  __syncthreads();
  for (int off = 1; off < 1024; off <<= 1) {
    int t = (tid >= off) ? sm[tid - off] : 0;
    __syncthreads();
    sm[tid] += t;
    __syncthreads();
  }
  if (idx < N_NODES) offsets[idx] = sm[tid];
  if (tid == 1023) bsums[blockIdx.x] = sm[1023];
}

__global__ void k_scan2(const int* __restrict__ bsums, int* __restrict__ bexcl) {
  int lane = threadIdx.x;
  int orig = (lane < 49) ? bsums[lane] : 0;
  int v = orig;
  for (int off = 1; off < 64; off <<= 1) {
    int u = __shfl_up(v, off, 64);
    if (lane >= off) v += u;
  }
  if (lane < 64) bexcl[lane] = v - orig;
}

__global__ __launch_bounds__(1024) void k_scan3(const int* __restrict__ counts,
                                                int* __restrict__ offsets,
                                                int* __restrict__ cursor,
                                                float* __restrict__ dis,
                                                int* __restrict__ elist,
                                                const int* __restrict__ bexcl) {
  int idx = blockIdx.x * 1024 + threadIdx.x;
  if (idx >= N_NODES) return;
  int val = counts[idx] + 1;
  int incl = offsets[idx] + bexcl[blockIdx.x];
  int excl = incl - val;
  offsets[idx] = excl;
  cursor[idx] = excl;
  dis[idx] = rsqrtf((float)val);
  elist[incl - 1] = idx;                    // self-loop in last slot
  if (idx == N_NODES - 1) offsets[N_NODES] = incl;  // == TOT_E
}

__global__ void k_fill(const int* __restrict__ ei, int* __restrict__ cursor,
                       int* __restrict__ elist) {
  int e = blockIdx.x * 256 + threadIdx.x;
  if (e >= N_EDGES) return;
  int s = ei[e], d = ei[N_EDGES + e];
  int pos = atomicAdd(&cursor[d], 1);
  elist[pos] = s;
}

// ---------------- weight repack ----------------
// Wb1: bf16 fragment-linear for mfma_f32_16x16x32_bf16 B-operand:
//   Wb1[((kb*4+cg)*64 + lane)*8 + j] = bf16(W1[k][c]),
//   k = kb*32 + (lane>>4)*8 + j, c = cg*16 + (lane&15)
__global__ void k_wprep(const float* __restrict__ W1, const float* __restrict__ W2,
                        unsigned short* __restrict__ Wb1, float* __restrict__ Wp2) {
  int i = blockIdx.x * 256 + threadIdx.x;
  if (i < IN_DIM * HID_DIM) {
    int j = i & 7;
    int lane = (i >> 3) & 63;
    int cg = (i >> 9) & 3;
    int kb = i >> 11;
    int k = kb * 32 + ((lane >> 4) << 3) + j;
    int c = cg * 16 + (lane & 15);
    Wb1[i] = f2bf(W1[k * HID_DIM + c]);
  }
  if (i < HID_DIM * OUT_DIM) {
    int k = i / OUT_DIM, c = i - k * OUT_DIM;
    Wp2[(k >> 2) * (OUT_DIM * 4) + (c << 2) + (k & 3)] = W2[i];
  }
}

// ---------------- GEMM1 (MFMA bf16): ht1s = dis[row] * (x @ W1) ----------------
// 64 rows/block, 4 waves (16 rows each), 4 col-groups of 16, K chunks of 64,
// x staged coalesced->bf16 LDS (stride 72 shorts = 144B), double-buffered.
__global__ __launch_bounds__(256) void k_gemm1(const float* __restrict__ x,
                                               const unsigned short* __restrict__ Wb1,
                                               const float* __restrict__ dis,
                                               float* __restrict__ ht1s) {
  __shared__ unsigned short sxa[2][64 * 72];
  const int tid = threadIdx.x;
  const int lane = tid & 63;
  const int wave = tid >> 6;          // 0..3 -> rows 16w..16w+15
  const int brow = blockIdx.x * 64;
  const int fq = tid & 15;            // k-quad for staging
  const int sr = tid >> 4;            // staging row base

  f32x4 acc[4];
#pragma unroll
  for (int cg = 0; cg < 4; ++cg) acc[cg] = (f32x4){0.f, 0.f, 0.f, 0.f};

  const bf16x8* __restrict__ Wv = (const bf16x8*)Wb1;

#define STAGE(B, K0)                                                          \
  {                                                                           \
    _Pragma("unroll")                                                         \
    for (int j = 0; j < 4; ++j) {                                             \
      int r = sr + j * 16;                                                    \
      int gr = brow + r;                                                      \
      if (gr >= N_NODES) gr = N_NODES - 1;                                    \
      float4 v = *(const float4*)(x + (size_t)gr * IN_DIM + (K0) + fq * 4);   \
      ushort4 o;                                                              \
      o.x = f2bf(v.x); o.y = f2bf(v.y); o.z = f2bf(v.z); o.w = f2bf(v.w);     \
      *(ushort4*)(&sxa[B][r * 72 + fq * 4]) = o;                              \
    }                                                                         \
  }

  STAGE(0, 0)
  __syncthreads();

  int buf = 0;
  for (int kc = 0; kc < IN_DIM / 64; ++kc) {
    if (kc < IN_DIM / 64 - 1) STAGE(buf ^ 1, (kc + 1) * 64)
#pragma unroll
    for (int ks = 0; ks < 2; ++ks) {
      bf16x8 a = *(const bf16x8*)(
          &sxa[buf][(16 * wave + (lane & 15)) * 72 + ks * 32 + ((lane >> 4) << 3)]);
      int kb = kc * 2 + ks;
#pragma unroll
      for (int cg = 0; cg < 4; ++cg) {
        bf16x8 b = Wv[(kb * 4 + cg) * 64 + lane];
        acc[cg] = __builtin_amdgcn_mfma_f32_16x16x32_bf16(a, b, acc[cg], 0, 0, 0);
      }
    }
    __syncthreads();
    buf ^= 1;
  }
#undef STAGE

#pragma unroll
  for (int q = 0; q < 4; ++q) {
    int grow = brow + 16 * wave + ((lane >> 4) << 2) + q;
    if (grow < N_NODES) {
      float dr = dis[grow];
#pragma unroll
      for (int cg = 0; cg < 4; ++cg) {
        ht1s[(size_t)grow * HID_DIM + cg * 16 + (lane & 15)] = acc[cg][q] * dr;
      }
    }
  }
}

// ---------------- agg1: h[d] = dropout(relu(dis[d]*sum ht1s[src] + b1)) -----
__global__ __launch_bounds__(256) void k_agg1(const int* __restrict__ offsets,
                                              const int* __restrict__ elist,
                                              const float* __restrict__ dis,
                                              const float* __restrict__ ht1s,
                                              const float* __restrict__ b1,
                                              float* __restrict__ h) {
  const int wave = threadIdx.x >> 6;
  const int lane = threadIdx.x & 63;
  const int d = blockIdx.x * 4 + wave;
  const int g = lane >> 4;        // edge group 0..3
  const int fl = lane & 15;       // feature quad 0..15

  const int begin = offsets[d], end = offsets[d + 1];
  float4 acc = {0.f, 0.f, 0.f, 0.f};
  for (int j = begin + g; j < end; j += 4) {
    int s = elist[j];
    const float4 v = *(const float4*)(ht1s + (size_t)s * HID_DIM + fl * 4);
    acc.x += v.x; acc.y += v.y; acc.z += v.z; acc.w += v.w;
  }
  acc.x += __shfl_xor(acc.x, 32); acc.y += __shfl_xor(acc.y, 32);
  acc.z += __shfl_xor(acc.z, 32); acc.w += __shfl_xor(acc.w, 32);
  acc.x += __shfl_xor(acc.x, 16); acc.y += __shfl_xor(acc.y, 16);
  acc.z += __shfl_xor(acc.z, 16); acc.w += __shfl_xor(acc.w, 16);

  if (lane < 16) {
    float dd = dis[d];
    float4 bb = *(const float4*)(b1 + lane * 4);
    float4 v;
    v.x = fmaxf(acc.x * dd + bb.x, 0.f);
    v.y = fmaxf(acc.y * dd + bb.y, 0.f);
    v.z = fmaxf(acc.z * dd + bb.z, 0.f);
    v.w = fmaxf(acc.w * dd + bb.w, 0.f);
    unsigned base = (unsigned)d * 64u + (unsigned)lane * 4u;
    unsigned o0, o1;
    threefry2x32_0_42(0u, base + 0u, o0, o1);
    v.x = ((o0 ^ o1) & 0x80000000u) ? 0.f : v.x * 2.f;
    threefry2x32_0_42(0u, base + 1u, o0, o1);
    v.y = ((o0 ^ o1) & 0x80000000u) ? 0.f : v.y * 2.f;
    threefry2x32_0_42(0u, base + 2u, o0, o1);
    v.z = ((o0 ^ o1) & 0x80000000u) ? 0.f : v.z * 2.f;
    threefry2x32_0_42(0u, base + 3u, o0, o1);
    v.w = ((o0 ^ o1) & 0x80000000u) ? 0.f : v.w * 2.f;
    *(float4*)(h + (size_t)d * HID_DIM + lane * 4) = v;
  }
}

// ---------------- GEMM2: ht2s = dis[row] * (h @ W2) ----------------
__global__ __launch_bounds__(256) void k_gemm2(const float* __restrict__ h,
                                               const float* __restrict__ Wp2,
                                               const float* __restrict__ dis,
                                               float* __restrict__ ht2s) {
  const int lane = threadIdx.x & 63;
  const int wave = threadIdx.x >> 6;                       // 0..3
  const int cg = __builtin_amdgcn_readfirstlane(wave & 1); // 0/1
  const int rb = wave >> 1;                                // 0/1
  const int row = blockIdx.x * 128 + rb * 64 + lane;
  const bool valid = row < N_NODES;
  const float4* __restrict__ hrow =
      (const float4*)(h + (size_t)(valid ? row : 0) * HID_DIM);

  float acc[20];
#pragma unroll
  for (int i = 0; i < 20; ++i) acc[i] = 0.0f;

#pragma unroll 2
  for (int k0 = 0; k0 < HID_DIM; k0 += 4) {
    float4 x4 = hrow[k0 >> 2];
    const float4* __restrict__ wv = (const float4*)(Wp2 + (k0 >> 2) * 160 + cg * 80);
#pragma unroll
    for (int c = 0; c < 20; ++c) {
      float4 w = wv[c];
      acc[c] += x4.x * w.x;
      acc[c] += x4.y * w.y;
      acc[c] += x4.z * w.z;
      acc[c] += x4.w * w.w;
    }
  }
  if (valid) {
    float dr = dis[row];
    float* __restrict__ o = ht2s + (size_t)row * OUT_DIM + cg * 20;
#pragma unroll
    for (int c = 0; c < 20; ++c) o[c] = acc[c] * dr;
  }
}

// ---------------- agg2 + bias2 + log-softmax, fused ----------------
__global__ __launch_bounds__(256) void k_agg2(const int* __restrict__ offsets,
                                              const int* __restrict__ elist,
                                              const float* __restrict__ dis,
                                              const float* __restrict__ ht2s,
                                              const float* __restrict__ b2,
                                              float* __restrict__ out) {
  const int wave = threadIdx.x >> 6;
  const int lane = threadIdx.x & 63;
  const int d = blockIdx.x * 4 + wave;

  const int begin = offsets[d], end = offsets[d + 1];
  float acc = 0.f;
  if (lane < OUT_DIM) {
    for (int j = begin; j < end; ++j) {
      int s = elist[j];
      acc += ht2s[(size_t)s * OUT_DIM + lane];
    }
  }
  float v = (lane < OUT_DIM) ? acc * dis[d] + b2[lane] : -FLT_MAX;
  float m = v;
  m = fmaxf(m, __shfl_xor(m, 1));
  m = fmaxf(m, __shfl_xor(m, 2));
  m = fmaxf(m, __shfl_xor(m, 4));
  m = fmaxf(m, __shfl_xor(m, 8));
  m = fmaxf(m, __shfl_xor(m, 16));
  m = fmaxf(m, __shfl_xor(m, 32));
  float e = (lane < OUT_DIM) ? expf(v - m) : 0.f;
  e += __shfl_xor(e, 1);
  e += __shfl_xor(e, 2);
  e += __shfl_xor(e, 4);
  e += __shfl_xor(e, 8);
  e += __shfl_xor(e, 16);
  e += __shfl_xor(e, 32);
  float ls = logf(e) + m;
  if (lane < OUT_DIM) out[(size_t)d * OUT_DIM + lane] = v - ls;
}

// ---------------- launch ----------------
extern "C" void kernel_launch(void* const* d_in, const int* in_sizes, int n_in,
                              void* d_out, int out_size, void* d_ws, size_t ws_size,
                              hipStream_t stream) {
  const float* x  = (const float*)d_in[0];
  const int*   ei = (const int*)  d_in[1];
  const float* W1 = (const float*)d_in[2];
  const float* b1 = (const float*)d_in[3];
  const float* W2 = (const float*)d_in[4];
  const float* b2 = (const float*)d_in[5];
  float* out = (float*)d_out;
  float* ws  = (float*)d_ws;

  // ws layout
  float* ht   = ws;                         // 3,200,000  (ht1s, later ht2s)
  float* h    = ws + 3200000;               // 3,200,000
  float* dis  = ws + 6400000;               // 51,200
  unsigned short* Wb1 = (unsigned short*)(ws + 6451200);  // 32768 ushorts (16384 floats)
  float* Wp2  = ws + 6483968;               // 2,560
  int* ibase  = (int*)(ws + 6486528);
  int* counts  = ibase;                     // 51,200
  int* offsets = ibase + 51200;             // 51,264 (needs 50001)
  int* cursor  = ibase + 102464;            // 51,200
  int* elist   = ibase + 153664;            // 850,000
  int* bsums   = ibase + 1003664;           // 64
  int* bexcl   = ibase + 1003728;           // 64

  hipMemsetAsync(counts, 0, (size_t)N_NODES * sizeof(int), stream);

  k_count<<<3125, 256, 0, stream>>>(ei + N_EDGES, counts);
  k_scan1<<<49, 1024, 0, stream>>>(counts, offsets, bsums);
  k_scan2<<<1, 64, 0, stream>>>(bsums, bexcl);
  k_scan3<<<49, 1024, 0, stream>>>(counts, offsets, cursor, dis, elist, bexcl);
  k_fill<<<3125, 256, 0, stream>>>(ei, cursor, elist);

  k_wprep<<<128, 256, 0, stream>>>(W1, W2, Wb1, Wp2);
  k_gemm1<<<782, 256, 0, stream>>>(x, Wb1, dis, ht);
  k_agg1<<<12500, 256, 0, stream>>>(offsets, elist, dis, ht, b1, h);
  k_gemm2<<<391, 256, 0, stream>>>(h, Wp2, dis, ht);
  k_agg2<<<12500, 256, 0, stream>>>(offsets, elist, dis, ht, b2, out);
}

// Round 8
// 240.922 us; speedup vs baseline: 1.5721x; 1.1173x over previous
//
#include <hip/hip_runtime.h>
#include <math.h>
#include <float.h>

#define N_NODES 50000
#define N_EDGES 800000
#define TOT_E   850000          // N_EDGES + N_NODES self loops
#define IN_DIM  512
#define HID_DIM 64
#define OUT_DIM 40

typedef __attribute__((ext_vector_type(8))) short bf16x8;
typedef __attribute__((ext_vector_type(4))) float f32x4;

// ---------------- Threefry-2x32, JAX-exact, key = (0, 42) ----------------
__device__ __forceinline__ unsigned rotl32(unsigned v, int n) {
  return (v << n) | (v >> (32 - n));
}

__device__ __forceinline__ void threefry2x32_0_42(unsigned x0, unsigned x1,
                                                  unsigned &o0, unsigned &o1) {
  const unsigned ks0 = 0u;
  const unsigned ks1 = 42u;
  const unsigned ks2 = 0u ^ 42u ^ 0x1BD11BDAu;
  x0 += ks0; x1 += ks1;
  x0 += x1; x1 = rotl32(x1, 13); x1 ^= x0;
  x0 += x1; x1 = rotl32(x1, 15); x1 ^= x0;
  x0 += x1; x1 = rotl32(x1, 26); x1 ^= x0;
  x0 += x1; x1 = rotl32(x1,  6); x1 ^= x0;
  x0 += ks1; x1 += ks2 + 1u;
  x0 += x1; x1 = rotl32(x1, 17); x1 ^= x0;
  x0 += x1; x1 = rotl32(x1, 29); x1 ^= x0;
  x0 += x1; x1 = rotl32(x1, 16); x1 ^= x0;
  x0 += x1; x1 = rotl32(x1, 24); x1 ^= x0;
  x0 += ks2; x1 += ks0 + 2u;
  x0 += x1; x1 = rotl32(x1, 13); x1 ^= x0;
  x0 += x1; x1 = rotl32(x1, 15); x1 ^= x0;
  x0 += x1; x1 = rotl32(x1, 26); x1 ^= x0;
  x0 += x1; x1 = rotl32(x1,  6); x1 ^= x0;
  x0 += ks0; x1 += ks1 + 3u;
  x0 += x1; x1 = rotl32(x1, 17); x1 ^= x0;
  x0 += x1; x1 = rotl32(x1, 29); x1 ^= x0;
  x0 += x1; x1 = rotl32(x1, 16); x1 ^= x0;
  x0 += x1; x1 = rotl32(x1, 24); x1 ^= x0;
  x0 += ks1; x1 += ks2 + 4u;
  x0 += x1; x1 = rotl32(x1, 13); x1 ^= x0;
  x0 += x1; x1 = rotl32(x1, 15); x1 ^= x0;
  x0 += x1; x1 = rotl32(x1, 26); x1 ^= x0;
  x0 += x1; x1 = rotl32(x1,  6); x1 ^= x0;
  x0 += ks2; x1 += ks0 + 5u;
  o0 = x0; o1 = x1;
}

__device__ __forceinline__ unsigned short f2bf(float f) {
  unsigned u = __float_as_uint(f);
  unsigned r = u + 0x7FFFu + ((u >> 16) & 1u);   // RNE
  return (unsigned short)(r >> 16);
}

// ---------------- CSR build ----------------
__global__ void k_count(const int* __restrict__ dst, int* __restrict__ counts) {
  int e = blockIdx.x * 256 + threadIdx.x;
  if (e < N_EDGES) atomicAdd(&counts[dst[e]], 1);
}

__global__ __launch_bounds__(1024) void k_scan1(const int* __restrict__ counts,
                                                int* __restrict__ offsets,
                                                int* __restrict__ bsums) {
  __shared__ int sm[1024];
  int tid = threadIdx.x;
  int idx = blockIdx.x * 1024 + tid;
  int val = (idx < N_NODES) ? counts[idx] + 1 : 0;
  sm[tid] = val;
  __syncthreads();
  for (int off = 1; off < 1024; off <<= 1) {
    int t = (tid >= off) ? sm[tid - off] : 0;
    __syncthreads();
    sm[tid] += t;
    __syncthreads();
  }
  if (idx < N_NODES) offsets[idx] = sm[tid];
  if (tid == 1023) bsums[blockIdx.x] = sm[1023];
}

__global__ void k_scan2(const int* __restrict__ bsums, int* __restrict__ bexcl) {
  int lane = threadIdx.x;
  int orig = (lane < 49) ? bsums[lane] : 0;
  int v = orig;
  for (int off = 1; off < 64; off <<= 1) {
    int u = __shfl_up(v, off, 64);
    if (lane >= off) v += u;
  }
  if (lane < 64) bexcl[lane] = v - orig;
}

__global__ __launch_bounds__(1024) void k_scan3(const int* __restrict__ counts,
                                                int* __restrict__ offsets,
                                                int* __restrict__ cursor,
                                                float* __restrict__ dis,
                                                int* __restrict__ elist,
                                                const int* __restrict__ bexcl) {
  int idx = blockIdx.x * 1024 + threadIdx.x;
  if (idx >= N_NODES) return;
  int val = counts[idx] + 1;
  int incl = offsets[idx] + bexcl[blockIdx.x];
  int excl = incl - val;
  offsets[idx] = excl;
  cursor[idx] = excl;
  dis[idx] = rsqrtf((float)val);
  elist[incl - 1] = idx;                    // self-loop in last slot
  if (idx == N_NODES - 1) offsets[N_NODES] = incl;  // == TOT_E
}

__global__ void k_fill(const int* __restrict__ ei, int* __restrict__ cursor,
                       int* __restrict__ elist) {
  int e = blockIdx.x * 256 + threadIdx.x;
  if (e >= N_EDGES) return;
  int s = ei[e], d = ei[N_EDGES + e];
  int pos = atomicAdd(&cursor[d], 1);
  elist[pos] = s;
}

// ---------------- weight repack ----------------
// Wb1: bf16 fragment-linear for mfma_f32_16x16x32_bf16 B-operand:
//   Wb1[((kb*4+cg)*64 + lane)*8 + j] = bf16(W1[k][c]),
//   k = kb*32 + (lane>>4)*8 + j, c = cg*16 + (lane&15)
__global__ void k_wprep(const float* __restrict__ W1, const float* __restrict__ W2,
                        unsigned short* __restrict__ Wb1, float* __restrict__ Wp2) {
  int i = blockIdx.x * 256 + threadIdx.x;
  if (i < IN_DIM * HID_DIM) {
    int j = i & 7;
    int lane = (i >> 3) & 63;
    int cg = (i >> 9) & 3;
    int kb = i >> 11;
    int k = kb * 32 + ((lane >> 4) << 3) + j;
    int c = cg * 16 + (lane & 15);
    Wb1[i] = f2bf(W1[k * HID_DIM + c]);
  }
  if (i < HID_DIM * OUT_DIM) {
    int k = i / OUT_DIM, c = i - k * OUT_DIM;
    Wp2[(k >> 2) * (OUT_DIM * 4) + (c << 2) + (k & 3)] = W2[i];
  }
}

// ---------------- GEMM1 (MFMA bf16): ht1s = dis[row] * (x @ W1) ----------------
__global__ __launch_bounds__(256) void k_gemm1(const float* __restrict__ x,
                                               const unsigned short* __restrict__ Wb1,
                                               const float* __restrict__ dis,
                                               float* __restrict__ ht1s) {
  __shared__ unsigned short sxa[2][64 * 72];
  const int tid = threadIdx.x;
  const int lane = tid & 63;
  const int wave = tid >> 6;          // 0..3 -> rows 16w..16w+15
  const int brow = blockIdx.x * 64;
  const int fq = tid & 15;            // k-quad for staging
  const int sr = tid >> 4;            // staging row base

  f32x4 acc[4];
#pragma unroll
  for (int cg = 0; cg < 4; ++cg) acc[cg] = (f32x4){0.f, 0.f, 0.f, 0.f};

  const bf16x8* __restrict__ Wv = (const bf16x8*)Wb1;

#define STAGE(B, K0)                                                          \
  {                                                                           \
    _Pragma("unroll")                                                         \
    for (int j = 0; j < 4; ++j) {                                             \
      int r = sr + j * 16;                                                    \
      int gr = brow + r;                                                      \
      if (gr >= N_NODES) gr = N_NODES - 1;                                    \
      float4 v = *(const float4*)(x + (size_t)gr * IN_DIM + (K0) + fq * 4);   \
      ushort4 o;                                                              \
      o.x = f2bf(v.x); o.y = f2bf(v.y); o.z = f2bf(v.z); o.w = f2bf(v.w);     \
      *(ushort4*)(&sxa[B][r * 72 + fq * 4]) = o;                              \
    }                                                                         \
  }

  STAGE(0, 0)
  __syncthreads();

  int buf = 0;
  for (int kc = 0; kc < IN_DIM / 64; ++kc) {
    if (kc < IN_DIM / 64 - 1) STAGE(buf ^ 1, (kc + 1) * 64)
#pragma unroll
    for (int ks = 0; ks < 2; ++ks) {
      bf16x8 a = *(const bf16x8*)(
          &sxa[buf][(16 * wave + (lane & 15)) * 72 + ks * 32 + ((lane >> 4) << 3)]);
      int kb = kc * 2 + ks;
#pragma unroll
      for (int cg = 0; cg < 4; ++cg) {
        bf16x8 b = Wv[(kb * 4 + cg) * 64 + lane];
        acc[cg] = __builtin_amdgcn_mfma_f32_16x16x32_bf16(a, b, acc[cg], 0, 0, 0);
      }
    }
    __syncthreads();
    buf ^= 1;
  }
#undef STAGE

#pragma unroll
  for (int q = 0; q < 4; ++q) {
    int grow = brow + 16 * wave + ((lane >> 4) << 2) + q;
    if (grow < N_NODES) {
      float dr = dis[grow];
#pragma unroll
      for (int cg = 0; cg < 4; ++cg) {
        ht1s[(size_t)grow * HID_DIM + cg * 16 + (lane & 15)] = acc[cg][q] * dr;
      }
    }
  }
}

// ---------------- agg1: h[d] = dropout(relu(dis[d]*sum ht1s[src] + b1)) -----
// wave per node: 8 edge-groups x 8 lanes x 2 float4 (8 edges in flight)
__global__ __launch_bounds__(256) void k_agg1(const int* __restrict__ offsets,
                                              const int* __restrict__ elist,
                                              const float* __restrict__ dis,
                                              const float* __restrict__ ht1s,
                                              const float* __restrict__ b1,
                                              float* __restrict__ h) {
  const int wave = threadIdx.x >> 6;
  const int lane = threadIdx.x & 63;
  const int d = blockIdx.x * 4 + wave;
  const int g = lane >> 3;        // edge group 0..7
  const int fh = lane & 7;        // feature quad pair: quads fh and fh+8

  const int begin = offsets[d], end = offsets[d + 1];
  float4 a0 = {0.f, 0.f, 0.f, 0.f};
  float4 a1 = {0.f, 0.f, 0.f, 0.f};
  for (int j = begin + g; j < end; j += 8) {
    int s = elist[j];
    const float4* __restrict__ p = (const float4*)(ht1s + (size_t)s * HID_DIM);
    float4 v0 = p[fh];
    float4 v1 = p[fh + 8];
    a0.x += v0.x; a0.y += v0.y; a0.z += v0.z; a0.w += v0.w;
    a1.x += v1.x; a1.y += v1.y; a1.z += v1.z; a1.w += v1.w;
  }
  // reduce over 8 groups (xor 32, 16, 8 keep fh bits)
#pragma unroll
  for (int m = 32; m >= 8; m >>= 1) {
    a0.x += __shfl_xor(a0.x, m); a0.y += __shfl_xor(a0.y, m);
    a0.z += __shfl_xor(a0.z, m); a0.w += __shfl_xor(a0.w, m);
    a1.x += __shfl_xor(a1.x, m); a1.y += __shfl_xor(a1.y, m);
    a1.z += __shfl_xor(a1.z, m); a1.w += __shfl_xor(a1.w, m);
  }

  if (lane < 8) {
    float dd = dis[d];
    float4 bb0 = *(const float4*)(b1 + fh * 4);
    float4 bb1 = *(const float4*)(b1 + fh * 4 + 32);
    float4 v0, v1;
    v0.x = fmaxf(a0.x * dd + bb0.x, 0.f);
    v0.y = fmaxf(a0.y * dd + bb0.y, 0.f);
    v0.z = fmaxf(a0.z * dd + bb0.z, 0.f);
    v0.w = fmaxf(a0.w * dd + bb0.w, 0.f);
    v1.x = fmaxf(a1.x * dd + bb1.x, 0.f);
    v1.y = fmaxf(a1.y * dd + bb1.y, 0.f);
    v1.z = fmaxf(a1.z * dd + bb1.z, 0.f);
    v1.w = fmaxf(a1.w * dd + bb1.w, 0.f);
    unsigned base = (unsigned)d * 64u + (unsigned)fh * 4u;
    unsigned o0, o1;
    threefry2x32_0_42(0u, base + 0u, o0, o1);
    v0.x = ((o0 ^ o1) & 0x80000000u) ? 0.f : v0.x * 2.f;
    threefry2x32_0_42(0u, base + 1u, o0, o1);
    v0.y = ((o0 ^ o1) & 0x80000000u) ? 0.f : v0.y * 2.f;
    threefry2x32_0_42(0u, base + 2u, o0, o1);
    v0.z = ((o0 ^ o1) & 0x80000000u) ? 0.f : v0.z * 2.f;
    threefry2x32_0_42(0u, base + 3u, o0, o1);
    v0.w = ((o0 ^ o1) & 0x80000000u) ? 0.f : v0.w * 2.f;
    threefry2x32_0_42(0u, base + 32u, o0, o1);
    v1.x = ((o0 ^ o1) & 0x80000000u) ? 0.f : v1.x * 2.f;
    threefry2x32_0_42(0u, base + 33u, o0, o1);
    v1.y = ((o0 ^ o1) & 0x80000000u) ? 0.f : v1.y * 2.f;
    threefry2x32_0_42(0u, base + 34u, o0, o1);
    v1.z = ((o0 ^ o1) & 0x80000000u) ? 0.f : v1.z * 2.f;
    threefry2x32_0_42(0u, base + 35u, o0, o1);
    v1.w = ((o0 ^ o1) & 0x80000000u) ? 0.f : v1.w * 2.f;
    *(float4*)(h + (size_t)d * HID_DIM + fh * 4) = v0;
    *(float4*)(h + (size_t)d * HID_DIM + fh * 4 + 32) = v1;
  }
}

// ---------------- GEMM2: ht2s = dis[row] * (h @ W2) ----------------
__global__ __launch_bounds__(256) void k_gemm2(const float* __restrict__ h,
                                               const float* __restrict__ Wp2,
                                               const float* __restrict__ dis,
                                               float* __restrict__ ht2s) {
  const int lane = threadIdx.x & 63;
  const int wave = threadIdx.x >> 6;                       // 0..3
  const int cg = __builtin_amdgcn_readfirstlane(wave & 1); // 0/1
  const int rb = wave >> 1;                                // 0/1
  const int row = blockIdx.x * 128 + rb * 64 + lane;
  const bool valid = row < N_NODES;
  const float4* __restrict__ hrow =
      (const float4*)(h + (size_t)(valid ? row : 0) * HID_DIM);

  float acc[20];
#pragma unroll
  for (int i = 0; i < 20; ++i) acc[i] = 0.0f;

#pragma unroll 2
  for (int k0 = 0; k0 < HID_DIM; k0 += 4) {
    float4 x4 = hrow[k0 >> 2];
    const float4* __restrict__ wv = (const float4*)(Wp2 + (k0 >> 2) * 160 + cg * 80);
#pragma unroll
    for (int c = 0; c < 20; ++c) {
      float4 w = wv[c];
      acc[c] += x4.x * w.x;
      acc[c] += x4.y * w.y;
      acc[c] += x4.z * w.z;
      acc[c] += x4.w * w.w;
    }
  }
  if (valid) {
    float dr = dis[row];
    float* __restrict__ o = ht2s + (size_t)row * OUT_DIM + cg * 20;
#pragma unroll
    for (int c = 0; c < 20; ++c) o[c] = acc[c] * dr;
  }
}

// ---------------- agg2 + bias2 + log-softmax, fused ----------------
// wave per node: 4 edge-groups x 16 lanes (10 active) x float4
__global__ __launch_bounds__(256) void k_agg2(const int* __restrict__ offsets,
                                              const int* __restrict__ elist,
                                              const float* __restrict__ dis,
                                              const float* __restrict__ ht2s,
                                              const float* __restrict__ b2,
                                              float* __restrict__ out) {
  const int wave = threadIdx.x >> 6;
  const int lane = threadIdx.x & 63;
  const int d = blockIdx.x * 4 + wave;
  const int g = lane >> 4;            // edge group 0..3
  const int fq = lane & 15;           // feature quad 0..9 active
  const int fqc = fq < 10 ? fq : 9;   // clamp idle lanes into the row

  const int begin = offsets[d], end = offsets[d + 1];
  float4 acc = {0.f, 0.f, 0.f, 0.f};
  for (int j = begin + g; j < end; j += 4) {
    int s = elist[j];
    float4 v = *(const float4*)(ht2s + (size_t)s * OUT_DIM + fqc * 4);
    acc.x += v.x; acc.y += v.y; acc.z += v.z; acc.w += v.w;
  }
  // reduce over 4 groups (xor 32, 16 keep fq bits)
  acc.x += __shfl_xor(acc.x, 32); acc.y += __shfl_xor(acc.y, 32);
  acc.z += __shfl_xor(acc.z, 32); acc.w += __shfl_xor(acc.w, 32);
  acc.x += __shfl_xor(acc.x, 16); acc.y += __shfl_xor(acc.y, 16);
  acc.z += __shfl_xor(acc.z, 16); acc.w += __shfl_xor(acc.w, 16);

  float dd = dis[d];
  float4 bb = *(const float4*)(b2 + fqc * 4);
  float4 v;
  v.x = acc.x * dd + bb.x;
  v.y = acc.y * dd + bb.y;
  v.z = acc.z * dd + bb.z;
  v.w = acc.w * dd + bb.w;

  float mm = (fq < 10) ? fmaxf(fmaxf(v.x, v.y), fmaxf(v.z, v.w)) : -FLT_MAX;
  mm = fmaxf(mm, __shfl_xor(mm, 1));
  mm = fmaxf(mm, __shfl_xor(mm, 2));
  mm = fmaxf(mm, __shfl_xor(mm, 4));
  mm = fmaxf(mm, __shfl_xor(mm, 8));
  float e = (fq < 10)
                ? (expf(v.x - mm) + expf(v.y - mm) + expf(v.z - mm) + expf(v.w - mm))
                : 0.f;
  e += __shfl_xor(e, 1);
  e += __shfl_xor(e, 2);
  e += __shfl_xor(e, 4);
  e += __shfl_xor(e, 8);
  float ls = logf(e) + mm;

  if (g == 0 && fq < 10) {
    float4 r;
    r.x = v.x - ls; r.y = v.y - ls; r.z = v.z - ls; r.w = v.w - ls;
    *(float4*)(out + (size_t)d * OUT_DIM + fq * 4) = r;
  }
}

// ---------------- launch ----------------
extern "C" void kernel_launch(void* const* d_in, const int* in_sizes, int n_in,
                              void* d_out, int out_size, void* d_ws, size_t ws_size,
                              hipStream_t stream) {
  const float* x  = (const float*)d_in[0];
  const int*   ei = (const int*)  d_in[1];
  const float* W1 = (const float*)d_in[2];
  const float* b1 = (const float*)d_in[3];
  const float* W2 = (const float*)d_in[4];
  const float* b2 = (const float*)d_in[5];
  float* out = (float*)d_out;
  float* ws  = (float*)d_ws;

  // ws layout
  float* ht   = ws;                         // 3,200,000  (ht1s, later ht2s)
  float* h    = ws + 3200000;               // 3,200,000
  float* dis  = ws + 6400000;               // 51,200
  unsigned short* Wb1 = (unsigned short*)(ws + 6451200);  // 32768 ushorts
  float* Wp2  = ws + 6483968;               // 2,560
  int* ibase  = (int*)(ws + 6486528);
  int* counts  = ibase;                     // 51,200
  int* offsets = ibase + 51200;             // 51,264 (needs 50001)
  int* cursor  = ibase + 102464;            // 51,200
  int* elist   = ibase + 153664;            // 850,000
  int* bsums   = ibase + 1003664;           // 64
  int* bexcl   = ibase + 1003728;           // 64

  hipMemsetAsync(counts, 0, (size_t)N_NODES * sizeof(int), stream);

  k_count<<<3125, 256, 0, stream>>>(ei + N_EDGES, counts);
  k_scan1<<<49, 1024, 0, stream>>>(counts, offsets, bsums);
  k_scan2<<<1, 64, 0, stream>>>(bsums, bexcl);
  k_scan3<<<49, 1024, 0, stream>>>(counts, offsets, cursor, dis, elist, bexcl);
  k_fill<<<3125, 256, 0, stream>>>(ei, cursor, elist);

  k_wprep<<<128, 256, 0, stream>>>(W1, W2, Wb1, Wp2);
  k_gemm1<<<782, 256, 0, stream>>>(x, Wb1, dis, ht);
  k_agg1<<<12500, 256, 0, stream>>>(offsets, elist, dis, ht, b1, h);
  k_gemm2<<<391, 256, 0, stream>>>(h, Wp2, dis, ht);
  k_agg2<<<12500, 256, 0, stream>>>(offsets, elist, dis, ht, b2, out);
}

// Round 9
// 205.194 us; speedup vs baseline: 1.8459x; 1.1741x over previous
//
#include <hip/hip_runtime.h>
#include <math.h>
#include <float.h>

#define N_NODES 50000
#define N_EDGES 800000
#define TOT_E   850000          // N_EDGES + N_NODES self loops
#define IN_DIM  512
#define HID_DIM 64
#define OUT_DIM 40

typedef __attribute__((ext_vector_type(8))) short bf16x8;
typedef __attribute__((ext_vector_type(4))) float f32x4;

// ---------------- Threefry-2x32, JAX-exact, key = (0, 42) ----------------
__device__ __forceinline__ unsigned rotl32(unsigned v, int n) {
  return (v << n) | (v >> (32 - n));
}

__device__ __forceinline__ void threefry2x32_0_42(unsigned x0, unsigned x1,
                                                  unsigned &o0, unsigned &o1) {
  const unsigned ks0 = 0u;
  const unsigned ks1 = 42u;
  const unsigned ks2 = 0u ^ 42u ^ 0x1BD11BDAu;
  x0 += ks0; x1 += ks1;
  x0 += x1; x1 = rotl32(x1, 13); x1 ^= x0;
  x0 += x1; x1 = rotl32(x1, 15); x1 ^= x0;
  x0 += x1; x1 = rotl32(x1, 26); x1 ^= x0;
  x0 += x1; x1 = rotl32(x1,  6); x1 ^= x0;
  x0 += ks1; x1 += ks2 + 1u;
  x0 += x1; x1 = rotl32(x1, 17); x1 ^= x0;
  x0 += x1; x1 = rotl32(x1, 29); x1 ^= x0;
  x0 += x1; x1 = rotl32(x1, 16); x1 ^= x0;
  x0 += x1; x1 = rotl32(x1, 24); x1 ^= x0;
  x0 += ks2; x1 += ks0 + 2u;
  x0 += x1; x1 = rotl32(x1, 13); x1 ^= x0;
  x0 += x1; x1 = rotl32(x1, 15); x1 ^= x0;
  x0 += x1; x1 = rotl32(x1, 26); x1 ^= x0;
  x0 += x1; x1 = rotl32(x1,  6); x1 ^= x0;
  x0 += ks0; x1 += ks1 + 3u;
  x0 += x1; x1 = rotl32(x1, 17); x1 ^= x0;
  x0 += x1; x1 = rotl32(x1, 29); x1 ^= x0;
  x0 += x1; x1 = rotl32(x1, 16); x1 ^= x0;
  x0 += x1; x1 = rotl32(x1, 24); x1 ^= x0;
  x0 += ks1; x1 += ks2 + 4u;
  x0 += x1; x1 = rotl32(x1, 13); x1 ^= x0;
  x0 += x1; x1 = rotl32(x1, 15); x1 ^= x0;
  x0 += x1; x1 = rotl32(x1, 26); x1 ^= x0;
  x0 += x1; x1 = rotl32(x1,  6); x1 ^= x0;
  x0 += ks2; x1 += ks0 + 5u;
  o0 = x0; o1 = x1;
}

__device__ __forceinline__ unsigned short f2bf(float f) {
  unsigned u = __float_as_uint(f);
  unsigned r = u + 0x7FFFu + ((u >> 16) & 1u);   // RNE
  return (unsigned short)(r >> 16);
}

// ---------------- CSR build ----------------
__global__ void k_count(const int* __restrict__ dst, int* __restrict__ counts) {
  int e = blockIdx.x * 256 + threadIdx.x;
  if (e < N_EDGES) atomicAdd(&counts[dst[e]], 1);
}

__global__ __launch_bounds__(1024) void k_scan1(const int* __restrict__ counts,
                                                int* __restrict__ offsets,
                                                int* __restrict__ bsums) {
  __shared__ int sm[1024];
  int tid = threadIdx.x;
  int idx = blockIdx.x * 1024 + tid;
  int val = (idx < N_NODES) ? counts[idx] + 1 : 0;
  sm[tid] = val;
  __syncthreads();
  for (int off = 1; off < 1024; off <<= 1) {
    int t = (tid >= off) ? sm[tid - off] : 0;
    __syncthreads();
    sm[tid] += t;
    __syncthreads();
  }
  if (idx < N_NODES) offsets[idx] = sm[tid];
  if (tid == 1023) bsums[blockIdx.x] = sm[1023];
}

__global__ void k_scan2(const int* __restrict__ bsums, int* __restrict__ bexcl) {
  int lane = threadIdx.x;
  int orig = (lane < 49) ? bsums[lane] : 0;
  int v = orig;
  for (int off = 1; off < 64; off <<= 1) {
    int u = __shfl_up(v, off, 64);
    if (lane >= off) v += u;
  }
  if (lane < 64) bexcl[lane] = v - orig;
}

__global__ __launch_bounds__(1024) void k_scan3(const int* __restrict__ counts,
                                                int* __restrict__ offsets,
                                                int* __restrict__ cursor,
                                                float* __restrict__ dis,
                                                int* __restrict__ elist,
                                                const int* __restrict__ bexcl) {
  int idx = blockIdx.x * 1024 + threadIdx.x;
  if (idx >= N_NODES) return;
  int val = counts[idx] + 1;
  int incl = offsets[idx] + bexcl[blockIdx.x];
  int excl = incl - val;
  offsets[idx] = excl;
  cursor[idx] = excl;
  dis[idx] = rsqrtf((float)val);
  elist[incl - 1] = idx;                    // self-loop in last slot
  if (idx == N_NODES - 1) offsets[N_NODES] = incl;  // == TOT_E
}

__global__ void k_fill(const int* __restrict__ ei, int* __restrict__ cursor,
                       int* __restrict__ elist) {
  int e = blockIdx.x * 256 + threadIdx.x;
  if (e >= N_EDGES) return;
  int s = ei[e], d = ei[N_EDGES + e];
  int pos = atomicAdd(&cursor[d], 1);
  elist[pos] = s;
}

// ---------------- weight repack ----------------
// Wb1: bf16 fragment-linear for mfma_f32_16x16x32_bf16 B-operand:
//   Wb1[((kb*4+cg)*64 + lane)*8 + j] = bf16(W1[k][c]),
//   k = kb*32 + (lane>>4)*8 + j, c = cg*16 + (lane&15)
__global__ void k_wprep(const float* __restrict__ W1, const float* __restrict__ W2,
                        unsigned short* __restrict__ Wb1, float* __restrict__ Wp2) {
  int i = blockIdx.x * 256 + threadIdx.x;
  if (i < IN_DIM * HID_DIM) {
    int j = i & 7;
    int lane = (i >> 3) & 63;
    int cg = (i >> 9) & 3;
    int kb = i >> 11;
    int k = kb * 32 + ((lane >> 4) << 3) + j;
    int c = cg * 16 + (lane & 15);
    Wb1[i] = f2bf(W1[k * HID_DIM + c]);
  }
  if (i < HID_DIM * OUT_DIM) {
    int k = i / OUT_DIM, c = i - k * OUT_DIM;
    Wp2[(k >> 2) * (OUT_DIM * 4) + (c << 2) + (k & 3)] = W2[i];
  }
}

// ---------------- GEMM1 (MFMA bf16): ht1s = dis[row] * (x @ W1) ----------------
__global__ __launch_bounds__(256) void k_gemm1(const float* __restrict__ x,
                                               const unsigned short* __restrict__ Wb1,
                                               const float* __restrict__ dis,
                                               float* __restrict__ ht1s) {
  __shared__ unsigned short sxa[2][64 * 72];
  const int tid = threadIdx.x;
  const int lane = tid & 63;
  const int wave = tid >> 6;          // 0..3 -> rows 16w..16w+15
  const int brow = blockIdx.x * 64;
  const int fq = tid & 15;            // k-quad for staging
  const int sr = tid >> 4;            // staging row base

  f32x4 acc[4];
#pragma unroll
  for (int cg = 0; cg < 4; ++cg) acc[cg] = (f32x4){0.f, 0.f, 0.f, 0.f};

  const bf16x8* __restrict__ Wv = (const bf16x8*)Wb1;

#define STAGE(B, K0)                                                          \
  {                                                                           \
    _Pragma("unroll")                                                         \
    for (int j = 0; j < 4; ++j) {                                             \
      int r = sr + j * 16;                                                    \
      int gr = brow + r;                                                      \
      if (gr >= N_NODES) gr = N_NODES - 1;                                    \
      float4 v = *(const float4*)(x + (size_t)gr * IN_DIM + (K0) + fq * 4);   \
      ushort4 o;                                                              \
      o.x = f2bf(v.x); o.y = f2bf(v.y); o.z = f2bf(v.z); o.w = f2bf(v.w);     \
      *(ushort4*)(&sxa[B][r * 72 + fq * 4]) = o;                              \
    }                                                                         \
  }

  STAGE(0, 0)
  __syncthreads();

  int buf = 0;
  for (int kc = 0; kc < IN_DIM / 64; ++kc) {
    if (kc < IN_DIM / 64 - 1) STAGE(buf ^ 1, (kc + 1) * 64)
#pragma unroll
    for (int ks = 0; ks < 2; ++ks) {
      bf16x8 a = *(const bf16x8*)(
          &sxa[buf][(16 * wave + (lane & 15)) * 72 + ks * 32 + ((lane >> 4) << 3)]);
      int kb = kc * 2 + ks;
#pragma unroll
      for (int cg = 0; cg < 4; ++cg) {
        bf16x8 b = Wv[(kb * 4 + cg) * 64 + lane];
        acc[cg] = __builtin_amdgcn_mfma_f32_16x16x32_bf16(a, b, acc[cg], 0, 0, 0);
      }
    }
    __syncthreads();
    buf ^= 1;
  }
#undef STAGE

#pragma unroll
  for (int q = 0; q < 4; ++q) {
    int grow = brow + 16 * wave + ((lane >> 4) << 2) + q;
    if (grow < N_NODES) {
      float dr = dis[grow];
#pragma unroll
      for (int cg = 0; cg < 4; ++cg) {
        ht1s[(size_t)grow * HID_DIM + cg * 16 + (lane & 15)] = acc[cg][q] * dr;
      }
    }
  }
}

// ---------------- agg1: h[d] = dropout(relu(dis[d]*sum ht1s[src] + b1)) -----
// wave per node: 8 edge-groups x 8 lanes x 2 float4; wave-parallel threefry
__global__ __launch_bounds__(256) void k_agg1(const int* __restrict__ offsets,
                                              const int* __restrict__ elist,
                                              const float* __restrict__ dis,
                                              const float* __restrict__ ht1s,
                                              const float* __restrict__ b1,
                                              float* __restrict__ h) {
  const int wave = threadIdx.x >> 6;
  const int lane = threadIdx.x & 63;
  const int d = blockIdx.x * 4 + wave;
  const int g = lane >> 3;        // edge group 0..7
  const int fh = lane & 7;        // feature quad pair: quads fh and fh+8

  // wave-parallel dropout mask: lane computes feature `lane`'s keep bit
  unsigned t0, t1;
  threefry2x32_0_42(0u, (unsigned)d * 64u + (unsigned)lane, t0, t1);
  unsigned long long keep = __ballot(!((t0 ^ t1) & 0x80000000u));

  const int begin = offsets[d], end = offsets[d + 1];
  float4 a0 = {0.f, 0.f, 0.f, 0.f};
  float4 a1 = {0.f, 0.f, 0.f, 0.f};
  for (int j = begin + g; j < end; j += 8) {
    int s = elist[j];
    const float4* __restrict__ p = (const float4*)(ht1s + (size_t)s * HID_DIM);
    float4 v0 = p[fh];
    float4 v1 = p[fh + 8];
    a0.x += v0.x; a0.y += v0.y; a0.z += v0.z; a0.w += v0.w;
    a1.x += v1.x; a1.y += v1.y; a1.z += v1.z; a1.w += v1.w;
  }
  // reduce over 8 groups (xor 32, 16, 8 keep fh bits)
#pragma unroll
  for (int m = 32; m >= 8; m >>= 1) {
    a0.x += __shfl_xor(a0.x, m); a0.y += __shfl_xor(a0.y, m);
    a0.z += __shfl_xor(a0.z, m); a0.w += __shfl_xor(a0.w, m);
    a1.x += __shfl_xor(a1.x, m); a1.y += __shfl_xor(a1.y, m);
    a1.z += __shfl_xor(a1.z, m); a1.w += __shfl_xor(a1.w, m);
  }

  if (lane < 8) {
    float dd = dis[d];
    float4 bb0 = *(const float4*)(b1 + fh * 4);
    float4 bb1 = *(const float4*)(b1 + fh * 4 + 32);
    int f0 = fh * 4;
    float4 v0, v1;
    v0.x = fmaxf(a0.x * dd + bb0.x, 0.f) * (((keep >> (f0 + 0)) & 1) ? 2.f : 0.f);
    v0.y = fmaxf(a0.y * dd + bb0.y, 0.f) * (((keep >> (f0 + 1)) & 1) ? 2.f : 0.f);
    v0.z = fmaxf(a0.z * dd + bb0.z, 0.f) * (((keep >> (f0 + 2)) & 1) ? 2.f : 0.f);
    v0.w = fmaxf(a0.w * dd + bb0.w, 0.f) * (((keep >> (f0 + 3)) & 1) ? 2.f : 0.f);
    v1.x = fmaxf(a1.x * dd + bb1.x, 0.f) * (((keep >> (f0 + 32)) & 1) ? 2.f : 0.f);
    v1.y = fmaxf(a1.y * dd + bb1.y, 0.f) * (((keep >> (f0 + 33)) & 1) ? 2.f : 0.f);
    v1.z = fmaxf(a1.z * dd + bb1.z, 0.f) * (((keep >> (f0 + 34)) & 1) ? 2.f : 0.f);
    v1.w = fmaxf(a1.w * dd + bb1.w, 0.f) * (((keep >> (f0 + 35)) & 1) ? 2.f : 0.f);
    *(float4*)(h + (size_t)d * HID_DIM + fh * 4) = v0;
    *(float4*)(h + (size_t)d * HID_DIM + fh * 4 + 32) = v1;
  }
}

// ---------------- GEMM2: ht2s = dis[row] * (h @ W2) ----------------
__global__ __launch_bounds__(256) void k_gemm2(const float* __restrict__ h,
                                               const float* __restrict__ Wp2,
                                               const float* __restrict__ dis,
                                               float* __restrict__ ht2s) {
  const int lane = threadIdx.x & 63;
  const int wave = threadIdx.x >> 6;                       // 0..3
  const int cg = __builtin_amdgcn_readfirstlane(wave & 1); // 0/1
  const int rb = wave >> 1;                                // 0/1
  const int row = blockIdx.x * 128 + rb * 64 + lane;
  const bool valid = row < N_NODES;
  const float4* __restrict__ hrow =
      (const float4*)(h + (size_t)(valid ? row : 0) * HID_DIM);

  float acc[20];
#pragma unroll
  for (int i = 0; i < 20; ++i) acc[i] = 0.0f;

#pragma unroll 2
  for (int k0 = 0; k0 < HID_DIM; k0 += 4) {
    float4 x4 = hrow[k0 >> 2];
    const float4* __restrict__ wv = (const float4*)(Wp2 + (k0 >> 2) * 160 + cg * 80);
#pragma unroll
    for (int c = 0; c < 20; ++c) {
      float4 w = wv[c];
      acc[c] += x4.x * w.x;
      acc[c] += x4.y * w.y;
      acc[c] += x4.z * w.z;
      acc[c] += x4.w * w.w;
    }
  }
  if (valid) {
    float dr = dis[row];
    float* __restrict__ o = ht2s + (size_t)row * OUT_DIM + cg * 20;
#pragma unroll
    for (int c = 0; c < 20; ++c) o[c] = acc[c] * dr;
  }
}

// ---------------- agg2 + bias2 + log-softmax, fused ----------------
// wave per node: 8 edge-groups x 8 lanes; lane carries quad fh, lanes 0-1 also 8+fh
__global__ __launch_bounds__(256) void k_agg2(const int* __restrict__ offsets,
                                              const int* __restrict__ elist,
                                              const float* __restrict__ dis,
                                              const float* __restrict__ ht2s,
                                              const float* __restrict__ b2,
                                              float* __restrict__ out) {
  const int wave = threadIdx.x >> 6;
  const int lane = threadIdx.x & 63;
  const int d = blockIdx.x * 4 + wave;
  const int g = lane >> 3;            // edge group 0..7
  const int fh = lane & 7;            // quad 0..7 (+ lanes 0,1 carry quads 8,9)
  const bool extra = fh < 2;

  const int begin = offsets[d], end = offsets[d + 1];
  float4 a0 = {0.f, 0.f, 0.f, 0.f};
  float4 a1 = {0.f, 0.f, 0.f, 0.f};
  for (int j = begin + g; j < end; j += 8) {
    int s = elist[j];
    const float4* __restrict__ p = (const float4*)(ht2s + (size_t)s * OUT_DIM);
    float4 v0 = p[fh];
    a0.x += v0.x; a0.y += v0.y; a0.z += v0.z; a0.w += v0.w;
    if (extra) {
      float4 v1 = p[8 + fh];
      a1.x += v1.x; a1.y += v1.y; a1.z += v1.z; a1.w += v1.w;
    }
  }
  // reduce over 8 groups (xor 32, 16, 8 keep fh bits)
#pragma unroll
  for (int m = 32; m >= 8; m >>= 1) {
    a0.x += __shfl_xor(a0.x, m); a0.y += __shfl_xor(a0.y, m);
    a0.z += __shfl_xor(a0.z, m); a0.w += __shfl_xor(a0.w, m);
    a1.x += __shfl_xor(a1.x, m); a1.y += __shfl_xor(a1.y, m);
    a1.z += __shfl_xor(a1.z, m); a1.w += __shfl_xor(a1.w, m);
  }

  float dd = dis[d];
  float4 bb0 = *(const float4*)(b2 + fh * 4);
  float4 v0, v1;
  v0.x = a0.x * dd + bb0.x;
  v0.y = a0.y * dd + bb0.y;
  v0.z = a0.z * dd + bb0.z;
  v0.w = a0.w * dd + bb0.w;
  float mm = fmaxf(fmaxf(v0.x, v0.y), fmaxf(v0.z, v0.w));
  if (extra) {
    float4 bb1 = *(const float4*)(b2 + 32 + fh * 4);
    v1.x = a1.x * dd + bb1.x;
    v1.y = a1.y * dd + bb1.y;
    v1.z = a1.z * dd + bb1.z;
    v1.w = a1.w * dd + bb1.w;
    mm = fmaxf(mm, fmaxf(fmaxf(v1.x, v1.y), fmaxf(v1.z, v1.w)));
  }
  mm = fmaxf(mm, __shfl_xor(mm, 1));
  mm = fmaxf(mm, __shfl_xor(mm, 2));
  mm = fmaxf(mm, __shfl_xor(mm, 4));
  float e = expf(v0.x - mm) + expf(v0.y - mm) + expf(v0.z - mm) + expf(v0.w - mm);
  if (extra)
    e += expf(v1.x - mm) + expf(v1.y - mm) + expf(v1.z - mm) + expf(v1.w - mm);
  e += __shfl_xor(e, 1);
  e += __shfl_xor(e, 2);
  e += __shfl_xor(e, 4);
  float ls = logf(e) + mm;

  if (g == 0) {
    float4 r;
    r.x = v0.x - ls; r.y = v0.y - ls; r.z = v0.z - ls; r.w = v0.w - ls;
    *(float4*)(out + (size_t)d * OUT_DIM + fh * 4) = r;
    if (extra) {
      float4 r1;
      r1.x = v1.x - ls; r1.y = v1.y - ls; r1.z = v1.z - ls; r1.w = v1.w - ls;
      *(float4*)(out + (size_t)d * OUT_DIM + 32 + fh * 4) = r1;
    }
  }
}

// ---------------- launch ----------------
extern "C" void kernel_launch(void* const* d_in, const int* in_sizes, int n_in,
                              void* d_out, int out_size, void* d_ws, size_t ws_size,
                              hipStream_t stream) {
  const float* x  = (const float*)d_in[0];
  const int*   ei = (const int*)  d_in[1];
  const float* W1 = (const float*)d_in[2];
  const float* b1 = (const float*)d_in[3];
  const float* W2 = (const float*)d_in[4];
  const float* b2 = (const float*)d_in[5];
  float* out = (float*)d_out;
  float* ws  = (float*)d_ws;

  // ws layout
  float* ht   = ws;                         // 3,200,000  (ht1s, later ht2s)
  float* h    = ws + 3200000;               // 3,200,000
  float* dis  = ws + 6400000;               // 51,200
  unsigned short* Wb1 = (unsigned short*)(ws + 6451200);  // 32768 ushorts
  float* Wp2  = ws + 6483968;               // 2,560
  int* ibase  = (int*)(ws + 6486528);
  int* counts  = ibase;                     // 51,200
  int* offsets = ibase + 51200;             // 51,264 (needs 50001)
  int* cursor  = ibase + 102464;            // 51,200
  int* elist   = ibase + 153664;            // 850,000
  int* bsums   = ibase + 1003664;           // 64
  int* bexcl   = ibase + 1003728;           // 64

  hipMemsetAsync(counts, 0, (size_t)N_NODES * sizeof(int), stream);

  k_count<<<3125, 256, 0, stream>>>(ei + N_EDGES, counts);
  k_scan1<<<49, 1024, 0, stream>>>(counts, offsets, bsums);
  k_scan2<<<1, 64, 0, stream>>>(bsums, bexcl);
  k_scan3<<<49, 1024, 0, stream>>>(counts, offsets, cursor, dis, elist, bexcl);
  k_fill<<<3125, 256, 0, stream>>>(ei, cursor, elist);

  k_wprep<<<128, 256, 0, stream>>>(W1, W2, Wb1, Wp2);
  k_gemm1<<<782, 256, 0, stream>>>(x, Wb1, dis, ht);
  k_agg1<<<12500, 256, 0, stream>>>(offsets, elist, dis, ht, b1, h);
  k_gemm2<<<391, 256, 0, stream>>>(h, Wp2, dis, ht);
  k_agg2<<<12500, 256, 0, stream>>>(offsets, elist, dis, ht, b2, out);
}

// Round 10
// 200.501 us; speedup vs baseline: 1.8891x; 1.0234x over previous
//
#include <hip/hip_runtime.h>
#include <math.h>
#include <float.h>

#define N_NODES 50000
#define N_EDGES 800000
#define TOT_E   850000          // N_EDGES + N_NODES self loops
#define IN_DIM  512
#define HID_DIM 64
#define OUT_DIM 40

typedef __attribute__((ext_vector_type(8))) short bf16x8;
typedef __attribute__((ext_vector_type(4))) float f32x4;

// ---------------- Threefry-2x32, JAX-exact, key = (0, 42) ----------------
__device__ __forceinline__ unsigned rotl32(unsigned v, int n) {
  return (v << n) | (v >> (32 - n));
}

__device__ __forceinline__ void threefry2x32_0_42(unsigned x0, unsigned x1,
                                                  unsigned &o0, unsigned &o1) {
  const unsigned ks0 = 0u;
  const unsigned ks1 = 42u;
  const unsigned ks2 = 0u ^ 42u ^ 0x1BD11BDAu;
  x0 += ks0; x1 += ks1;
  x0 += x1; x1 = rotl32(x1, 13); x1 ^= x0;
  x0 += x1; x1 = rotl32(x1, 15); x1 ^= x0;
  x0 += x1; x1 = rotl32(x1, 26); x1 ^= x0;
  x0 += x1; x1 = rotl32(x1,  6); x1 ^= x0;
  x0 += ks1; x1 += ks2 + 1u;
  x0 += x1; x1 = rotl32(x1, 17); x1 ^= x0;
  x0 += x1; x1 = rotl32(x1, 29); x1 ^= x0;
  x0 += x1; x1 = rotl32(x1, 16); x1 ^= x0;
  x0 += x1; x1 = rotl32(x1, 24); x1 ^= x0;
  x0 += ks2; x1 += ks0 + 2u;
  x0 += x1; x1 = rotl32(x1, 13); x1 ^= x0;
  x0 += x1; x1 = rotl32(x1, 15); x1 ^= x0;
  x0 += x1; x1 = rotl32(x1, 26); x1 ^= x0;
  x0 += x1; x1 = rotl32(x1,  6); x1 ^= x0;
  x0 += ks0; x1 += ks1 + 3u;
  x0 += x1; x1 = rotl32(x1, 17); x1 ^= x0;
  x0 += x1; x1 = rotl32(x1, 29); x1 ^= x0;
  x0 += x1; x1 = rotl32(x1, 16); x1 ^= x0;
  x0 += x1; x1 = rotl32(x1, 24); x1 ^= x0;
  x0 += ks1; x1 += ks2 + 4u;
  x0 += x1; x1 = rotl32(x1, 13); x1 ^= x0;
  x0 += x1; x1 = rotl32(x1, 15); x1 ^= x0;
  x0 += x1; x1 = rotl32(x1, 26); x1 ^= x0;
  x0 += x1; x1 = rotl32(x1,  6); x1 ^= x0;
  x0 += ks2; x1 += ks0 + 5u;
  o0 = x0; o1 = x1;
}

__device__ __forceinline__ unsigned short f2bf(float f) {
  unsigned u = __float_as_uint(f);
  unsigned r = u + 0x7FFFu + ((u >> 16) & 1u);   // RNE
  return (unsigned short)(r >> 16);
}

// ---------------- CSR build ----------------
__global__ void k_zero(int* __restrict__ c) {
  int i = blockIdx.x * 256 + threadIdx.x;
  if (i < N_NODES) c[i] = 0;
}

__global__ void k_count(const int* __restrict__ dst, int* __restrict__ counts) {
  int e = blockIdx.x * 256 + threadIdx.x;
  if (e < N_EDGES) atomicAdd(&counts[dst[e]], 1);
}

__global__ __launch_bounds__(1024) void k_scan1(const int* __restrict__ counts,
                                                int* __restrict__ offsets,
                                                int* __restrict__ bsums) {
  __shared__ int sm[1024];
  int tid = threadIdx.x;
  int idx = blockIdx.x * 1024 + tid;
  int val = (idx < N_NODES) ? counts[idx] + 1 : 0;
  sm[tid] = val;
  __syncthreads();
  for (int off = 1; off < 1024; off <<= 1) {
    int t = (tid >= off) ? sm[tid - off] : 0;
    __syncthreads();
    sm[tid] += t;
    __syncthreads();
  }
  if (idx < N_NODES) offsets[idx] = sm[tid];
  if (tid == 1023) bsums[blockIdx.x] = sm[1023];
}

__global__ void k_scan2(const int* __restrict__ bsums, int* __restrict__ bexcl) {
  int lane = threadIdx.x;
  int orig = (lane < 49) ? bsums[lane] : 0;
  int v = orig;
  for (int off = 1; off < 64; off <<= 1) {
    int u = __shfl_up(v, off, 64);
    if (lane >= off) v += u;
  }
  if (lane < 64) bexcl[lane] = v - orig;
}

__global__ __launch_bounds__(1024) void k_scan3(const int* __restrict__ counts,
                                                int* __restrict__ offsets,
                                                int* __restrict__ cursor,
                                                float* __restrict__ dis,
                                                int* __restrict__ elist,
                                                const int* __restrict__ bexcl) {
  int idx = blockIdx.x * 1024 + threadIdx.x;
  if (idx >= N_NODES) return;
  int val = counts[idx] + 1;
  int incl = offsets[idx] + bexcl[blockIdx.x];
  int excl = incl - val;
  offsets[idx] = excl;
  cursor[idx] = excl;
  dis[idx] = rsqrtf((float)val);
  elist[incl - 1] = idx;                    // self-loop in last slot
  if (idx == N_NODES - 1) offsets[N_NODES] = incl;  // == TOT_E
}

__global__ void k_fill(const int* __restrict__ ei, int* __restrict__ cursor,
                       int* __restrict__ elist) {
  int e = blockIdx.x * 256 + threadIdx.x;
  if (e >= N_EDGES) return;
  int s = ei[e], d = ei[N_EDGES + e];
  int pos = atomicAdd(&cursor[d], 1);
  elist[pos] = s;
}

// ---------------- weight repack ----------------
__global__ void k_wprep(const float* __restrict__ W1, const float* __restrict__ W2,
                        unsigned short* __restrict__ Wb1, float* __restrict__ Wp2) {
  int i = blockIdx.x * 256 + threadIdx.x;
  if (i < IN_DIM * HID_DIM) {
    int j = i & 7;
    int lane = (i >> 3) & 63;
    int cg = (i >> 9) & 3;
    int kb = i >> 11;
    int k = kb * 32 + ((lane >> 4) << 3) + j;
    int c = cg * 16 + (lane & 15);
    Wb1[i] = f2bf(W1[k * HID_DIM + c]);
  }
  if (i < HID_DIM * OUT_DIM) {
    int k = i / OUT_DIM, c = i - k * OUT_DIM;
    Wp2[(k >> 2) * (OUT_DIM * 4) + (c << 2) + (k & 3)] = W2[i];
  }
}

// ---------------- GEMM1 (MFMA bf16): ht1b = bf16(dis[row] * (x @ W1)) --------
__global__ __launch_bounds__(256) void k_gemm1(const float* __restrict__ x,
                                               const unsigned short* __restrict__ Wb1,
                                               const float* __restrict__ dis,
                                               unsigned short* __restrict__ ht1b) {
  __shared__ unsigned short sxa[2][64 * 72];
  const int tid = threadIdx.x;
  const int lane = tid & 63;
  const int wave = tid >> 6;          // 0..3 -> rows 16w..16w+15
  const int brow = blockIdx.x * 64;
  const int fq = tid & 15;            // k-quad for staging
  const int sr = tid >> 4;            // staging row base

  f32x4 acc[4];
#pragma unroll
  for (int cg = 0; cg < 4; ++cg) acc[cg] = (f32x4){0.f, 0.f, 0.f, 0.f};

  const bf16x8* __restrict__ Wv = (const bf16x8*)Wb1;

#define STAGE(B, K0)                                                          \
  {                                                                           \
    _Pragma("unroll")                                                         \
    for (int j = 0; j < 4; ++j) {                                             \
      int r = sr + j * 16;                                                    \
      int gr = brow + r;                                                      \
      if (gr >= N_NODES) gr = N_NODES - 1;                                    \
      float4 v = *(const float4*)(x + (size_t)gr * IN_DIM + (K0) + fq * 4);   \
      ushort4 o;                                                              \
      o.x = f2bf(v.x); o.y = f2bf(v.y); o.z = f2bf(v.z); o.w = f2bf(v.w);     \
      *(ushort4*)(&sxa[B][r * 72 + fq * 4]) = o;                              \
    }                                                                         \
  }

  STAGE(0, 0)
  __syncthreads();

  int buf = 0;
  for (int kc = 0; kc < IN_DIM / 64; ++kc) {
    if (kc < IN_DIM / 64 - 1) STAGE(buf ^ 1, (kc + 1) * 64)
#pragma unroll
    for (int ks = 0; ks < 2; ++ks) {
      bf16x8 a = *(const bf16x8*)(
          &sxa[buf][(16 * wave + (lane & 15)) * 72 + ks * 32 + ((lane >> 4) << 3)]);
      int kb = kc * 2 + ks;
#pragma unroll
      for (int cg = 0; cg < 4; ++cg) {
        bf16x8 b = Wv[(kb * 4 + cg) * 64 + lane];
        acc[cg] = __builtin_amdgcn_mfma_f32_16x16x32_bf16(a, b, acc[cg], 0, 0, 0);
      }
    }
    __syncthreads();
    buf ^= 1;
  }
#undef STAGE

#pragma unroll
  for (int q = 0; q < 4; ++q) {
    int grow = brow + 16 * wave + ((lane >> 4) << 2) + q;
    if (grow < N_NODES) {
      float dr = dis[grow];
#pragma unroll
      for (int cg = 0; cg < 4; ++cg) {
        ht1b[(size_t)grow * HID_DIM + cg * 16 + (lane & 15)] = f2bf(acc[cg][q] * dr);
      }
    }
  }
}

// ---------------- agg1: h[d] = dropout(relu(dis[d]*sum ht1b[src] + b1)) -----
// wave per node: 8 edge-groups x 8 lanes x 2 bf16-quads; wave-parallel threefry
__global__ __launch_bounds__(256) void k_agg1(const int* __restrict__ offsets,
                                              const int* __restrict__ elist,
                                              const float* __restrict__ dis,
                                              const unsigned short* __restrict__ ht1b,
                                              const float* __restrict__ b1,
                                              float* __restrict__ h) {
  const int wave = threadIdx.x >> 6;
  const int lane = threadIdx.x & 63;
  const int d = blockIdx.x * 4 + wave;
  const int g = lane >> 3;        // edge group 0..7
  const int fh = lane & 7;        // feature quad pair: quads fh and fh+8

  // wave-parallel dropout mask: lane computes feature `lane`'s keep bit
  unsigned t0, t1;
  threefry2x32_0_42(0u, (unsigned)d * 64u + (unsigned)lane, t0, t1);
  unsigned long long keep = __ballot(!((t0 ^ t1) & 0x80000000u));

  const int begin = offsets[d], end = offsets[d + 1];
  float4 a0 = {0.f, 0.f, 0.f, 0.f};
  float4 a1 = {0.f, 0.f, 0.f, 0.f};
  for (int j = begin + g; j < end; j += 8) {
    int s = elist[j];
    const uint2* __restrict__ p = (const uint2*)(ht1b + (size_t)s * HID_DIM);
    uint2 q0 = p[fh];
    uint2 q1 = p[fh + 8];
    a0.x += __uint_as_float(q0.x << 16);
    a0.y += __uint_as_float(q0.x & 0xFFFF0000u);
    a0.z += __uint_as_float(q0.y << 16);
    a0.w += __uint_as_float(q0.y & 0xFFFF0000u);
    a1.x += __uint_as_float(q1.x << 16);
    a1.y += __uint_as_float(q1.x & 0xFFFF0000u);
    a1.z += __uint_as_float(q1.y << 16);
    a1.w += __uint_as_float(q1.y & 0xFFFF0000u);
  }
  // reduce over 8 groups (xor 32, 16, 8 keep fh bits)
#pragma unroll
  for (int m = 32; m >= 8; m >>= 1) {
    a0.x += __shfl_xor(a0.x, m); a0.y += __shfl_xor(a0.y, m);
    a0.z += __shfl_xor(a0.z, m); a0.w += __shfl_xor(a0.w, m);
    a1.x += __shfl_xor(a1.x, m); a1.y += __shfl_xor(a1.y, m);
    a1.z += __shfl_xor(a1.z, m); a1.w += __shfl_xor(a1.w, m);
  }

  if (lane < 8) {
    float dd = dis[d];
    float4 bb0 = *(const float4*)(b1 + fh * 4);
    float4 bb1 = *(const float4*)(b1 + fh * 4 + 32);
    int f0 = fh * 4;
    float4 v0, v1;
    v0.x = fmaxf(a0.x * dd + bb0.x, 0.f) * (((keep >> (f0 + 0)) & 1) ? 2.f : 0.f);
    v0.y = fmaxf(a0.y * dd + bb0.y, 0.f) * (((keep >> (f0 + 1)) & 1) ? 2.f : 0.f);
    v0.z = fmaxf(a0.z * dd + bb0.z, 0.f) * (((keep >> (f0 + 2)) & 1) ? 2.f : 0.f);
    v0.w = fmaxf(a0.w * dd + bb0.w, 0.f) * (((keep >> (f0 + 3)) & 1) ? 2.f : 0.f);
    v1.x = fmaxf(a1.x * dd + bb1.x, 0.f) * (((keep >> (f0 + 32)) & 1) ? 2.f : 0.f);
    v1.y = fmaxf(a1.y * dd + bb1.y, 0.f) * (((keep >> (f0 + 33)) & 1) ? 2.f : 0.f);
    v1.z = fmaxf(a1.z * dd + bb1.z, 0.f) * (((keep >> (f0 + 34)) & 1) ? 2.f : 0.f);
    v1.w = fmaxf(a1.w * dd + bb1.w, 0.f) * (((keep >> (f0 + 35)) & 1) ? 2.f : 0.f);
    *(float4*)(h + (size_t)d * HID_DIM + fh * 4) = v0;
    *(float4*)(h + (size_t)d * HID_DIM + fh * 4 + 32) = v1;
  }
}

// ---------------- GEMM2: ht2b = bf16(dis[row] * (h @ W2)) ----------------
__global__ __launch_bounds__(256) void k_gemm2(const float* __restrict__ h,
                                               const float* __restrict__ Wp2,
                                               const float* __restrict__ dis,
                                               unsigned short* __restrict__ ht2b) {
  const int lane = threadIdx.x & 63;
  const int wave = threadIdx.x >> 6;                       // 0..3
  const int cg = __builtin_amdgcn_readfirstlane(wave & 1); // 0/1
  const int rb = wave >> 1;                                // 0/1
  const int row = blockIdx.x * 128 + rb * 64 + lane;
  const bool valid = row < N_NODES;
  const float4* __restrict__ hrow =
      (const float4*)(h + (size_t)(valid ? row : 0) * HID_DIM);

  float acc[20];
#pragma unroll
  for (int i = 0; i < 20; ++i) acc[i] = 0.0f;

#pragma unroll 2
  for (int k0 = 0; k0 < HID_DIM; k0 += 4) {
    float4 x4 = hrow[k0 >> 2];
    const float4* __restrict__ wv = (const float4*)(Wp2 + (k0 >> 2) * 160 + cg * 80);
#pragma unroll
    for (int c = 0; c < 20; ++c) {
      float4 w = wv[c];
      acc[c] += x4.x * w.x;
      acc[c] += x4.y * w.y;
      acc[c] += x4.z * w.z;
      acc[c] += x4.w * w.w;
    }
  }
  if (valid) {
    float dr = dis[row];
    ushort2* __restrict__ o = (ushort2*)(ht2b + (size_t)row * OUT_DIM + cg * 20);
#pragma unroll
    for (int c = 0; c < 10; ++c) {
      ushort2 p;
      p.x = f2bf(acc[2 * c] * dr);
      p.y = f2bf(acc[2 * c + 1] * dr);
      o[c] = p;
    }
  }
}

// ---------------- agg2 + bias2 + log-softmax, fused ----------------
// wave per node: 8 edge-groups x 8 lanes; lane carries quad fh, lanes 0-1 also 8+fh
__global__ __launch_bounds__(256) void k_agg2(const int* __restrict__ offsets,
                                              const int* __restrict__ elist,
                                              const float* __restrict__ dis,
                                              const unsigned short* __restrict__ ht2b,
                                              const float* __restrict__ b2,
                                              float* __restrict__ out) {
  const int wave = threadIdx.x >> 6;
  const int lane = threadIdx.x & 63;
  const int d = blockIdx.x * 4 + wave;
  const int g = lane >> 3;            // edge group 0..7
  const int fh = lane & 7;            // quad 0..7 (+ lanes 0,1 carry quads 8,9)
  const bool extra = fh < 2;

  const int begin = offsets[d], end = offsets[d + 1];
  float4 a0 = {0.f, 0.f, 0.f, 0.f};
  float4 a1 = {0.f, 0.f, 0.f, 0.f};
  for (int j = begin + g; j < end; j += 8) {
    int s = elist[j];
    const uint2* __restrict__ p = (const uint2*)(ht2b + (size_t)s * OUT_DIM);
    uint2 q0 = p[fh];
    a0.x += __uint_as_float(q0.x << 16);
    a0.y += __uint_as_float(q0.x & 0xFFFF0000u);
    a0.z += __uint_as_float(q0.y << 16);
    a0.w += __uint_as_float(q0.y & 0xFFFF0000u);
    if (extra) {
      uint2 q1 = p[8 + fh];
      a1.x += __uint_as_float(q1.x << 16);
      a1.y += __uint_as_float(q1.x & 0xFFFF0000u);
      a1.z += __uint_as_float(q1.y << 16);
      a1.w += __uint_as_float(q1.y & 0xFFFF0000u);
    }
  }
  // reduce over 8 groups (xor 32, 16, 8 keep fh bits)
#pragma unroll
  for (int m = 32; m >= 8; m >>= 1) {
    a0.x += __shfl_xor(a0.x, m); a0.y += __shfl_xor(a0.y, m);
    a0.z += __shfl_xor(a0.z, m); a0.w += __shfl_xor(a0.w, m);
    a1.x += __shfl_xor(a1.x, m); a1.y += __shfl_xor(a1.y, m);
    a1.z += __shfl_xor(a1.z, m); a1.w += __shfl_xor(a1.w, m);
  }

  float dd = dis[d];
  float4 bb0 = *(const float4*)(b2 + fh * 4);
  float4 v0, v1;
  v0.x = a0.x * dd + bb0.x;
  v0.y = a0.y * dd + bb0.y;
  v0.z = a0.z * dd + bb0.z;
  v0.w = a0.w * dd + bb0.w;
  float mm = fmaxf(fmaxf(v0.x, v0.y), fmaxf(v0.z, v0.w));
  if (extra) {
    float4 bb1 = *(const float4*)(b2 + 32 + fh * 4);
    v1.x = a1.x * dd + bb1.x;
    v1.y = a1.y * dd + bb1.y;
    v1.z = a1.z * dd + bb1.z;
    v1.w = a1.w * dd + bb1.w;
    mm = fmaxf(mm, fmaxf(fmaxf(v1.x, v1.y), fmaxf(v1.z, v1.w)));
  }
  mm = fmaxf(mm, __shfl_xor(mm, 1));
  mm = fmaxf(mm, __shfl_xor(mm, 2));
  mm = fmaxf(mm, __shfl_xor(mm, 4));
  float e = expf(v0.x - mm) + expf(v0.y - mm) + expf(v0.z - mm) + expf(v0.w - mm);
  if (extra)
    e += expf(v1.x - mm) + expf(v1.y - mm) + expf(v1.z - mm) + expf(v1.w - mm);
  e += __shfl_xor(e, 1);
  e += __shfl_xor(e, 2);
  e += __shfl_xor(e, 4);
  float ls = logf(e) + mm;

  if (g == 0) {
    float4 r;
    r.x = v0.x - ls; r.y = v0.y - ls; r.z = v0.z - ls; r.w = v0.w - ls;
    *(float4*)(out + (size_t)d * OUT_DIM + fh * 4) = r;
    if (extra) {
      float4 r1;
      r1.x = v1.x - ls; r1.y = v1.y - ls; r1.z = v1.z - ls; r1.w = v1.w - ls;
      *(float4*)(out + (size_t)d * OUT_DIM + 32 + fh * 4) = r1;
    }
  }
}

// ---------------- launch ----------------
extern "C" void kernel_launch(void* const* d_in, const int* in_sizes, int n_in,
                              void* d_out, int out_size, void* d_ws, size_t ws_size,
                              hipStream_t stream) {
  const float* x  = (const float*)d_in[0];
  const int*   ei = (const int*)  d_in[1];
  const float* W1 = (const float*)d_in[2];
  const float* b1 = (const float*)d_in[3];
  const float* W2 = (const float*)d_in[4];
  const float* b2 = (const float*)d_in[5];
  float* out = (float*)d_out;
  float* ws  = (float*)d_ws;

  // ws layout
  unsigned short* htb = (unsigned short*)ws; // 3.2M ushorts (ht1b) / 2M (ht2b)
  float* h    = ws + 3200000;               // 3,200,000
  float* dis  = ws + 6400000;               // 51,200
  unsigned short* Wb1 = (unsigned short*)(ws + 6451200);  // 32768 ushorts
  float* Wp2  = ws + 6483968;               // 2,560
  int* ibase  = (int*)(ws + 6486528);
  int* counts  = ibase;                     // 51,200
  int* offsets = ibase + 51200;             // 51,264 (needs 50001)
  int* cursor  = ibase + 102464;            // 51,200
  int* elist   = ibase + 153664;            // 850,000
  int* bsums   = ibase + 1003664;           // 64
  int* bexcl   = ibase + 1003728;           // 64

  k_zero<<<196, 256, 0, stream>>>(counts);
  k_count<<<3125, 256, 0, stream>>>(ei + N_EDGES, counts);
  k_scan1<<<49, 1024, 0, stream>>>(counts, offsets, bsums);
  k_scan2<<<1, 64, 0, stream>>>(bsums, bexcl);
  k_scan3<<<49, 1024, 0, stream>>>(counts, offsets, cursor, dis, elist, bexcl);
  k_fill<<<3125, 256, 0, stream>>>(ei, cursor, elist);

  k_wprep<<<128, 256, 0, stream>>>(W1, W2, Wb1, Wp2);
  k_gemm1<<<782, 256, 0, stream>>>(x, Wb1, dis, htb);
  k_agg1<<<12500, 256, 0, stream>>>(offsets, elist, dis, htb, b1, h);
  k_gemm2<<<391, 256, 0, stream>>>(h, Wp2, dis, htb);
  k_agg2<<<12500, 256, 0, stream>>>(offsets, elist, dis, htb, b2, out);
}